// Round 17
// baseline (90.208 us; speedup 1.0000x reference)
//
#include <hip/hip_runtime.h>
#include <hip/hip_bf16.h>
#include <cstddef>

#define B_ 4
#define T_ 12
#define N_ 512
#define D_ 256
#define H_ 4
#define SEG_ 6
#define BT_ (B_*T_)

#define SCALE_S 0.35355339059327373f   /* 8^-0.5  */
#define SCALE_H 0.25f                  /* 16^-0.5 */
#define LOG2E   1.44269504088896340736f
#define LAMBDA_INIT 0.2f
#define EPS_ 1e-6f

typedef short bf16x8 __attribute__((ext_vector_type(8)));
typedef float f32x4 __attribute__((ext_vector_type(4)));
typedef unsigned short us8 __attribute__((ext_vector_type(8)));
typedef unsigned short us4 __attribute__((ext_vector_type(4)));

__device__ inline float b2f(unsigned short u) {
    union { unsigned int i; float f; } x; x.i = ((unsigned int)u) << 16; return x.f;
}
// library convert (RNE + NaN handling) — prep only
__device__ inline unsigned short f2bs(float f) {
    __hip_bfloat16 b = __float2bfloat16(f);
    return *(unsigned short*)&b;
}
// fast 2-op bf16 pack (round-half-up; finite values) — hot loops
__device__ inline unsigned short f2bs_r(float f) {
    union { float f; unsigned int u; } x; x.f = f;
    return (unsigned short)((x.u + 0x8000u) >> 16);
}

#define GLOAD16(gsrc, ldst) \
    __builtin_amdgcn_global_load_lds((const __attribute__((address_space(1))) void*)(gsrc), \
                                     (__attribute__((address_space(3))) void*)(ldst), 16, 0, 0)

// ===========================================================================
// prep_all: blocks [0,4370) = fp32->bf16 conversions;
//           blocks [4370,4386) = Wagg fold into Weff cols [64,128) + bvec.
// Conv branch SKIPS Weff cols [64,128) — fold blocks are the sole writers.
// ===========================================================================
struct ConvArgs {
    const float* x; const float* d0; const float* d1;
    const float* wp[16];
    const float* bagg;
    unsigned short* xb; unsigned short* d0b; unsigned short* d1b; unsigned short* wb;
    float* bvec;
};
#define CSEG0 6291456
#define CSEG1 (CSEG0 + 786432)
#define CSEG2 (CSEG1 + 1572864)
#define CTOT  (CSEG2 + 299008)
#define NCONVBLK 4370   /* CTOT/8/256 */

__global__ __launch_bounds__(256) void prep_all(ConvArgs a)
{
    __shared__ float waggl[64 * 64];
    __shared__ float woutl[16 * 64];

    if (blockIdx.x >= NCONVBLK) {
        const float* wout = a.wp[15];
        const float* wagg = a.wp[14];
        unsigned short* weff = a.wb + 233472;
        const int tid = threadIdx.x;
        const int e0 = (blockIdx.x - NCONVBLK) * 16;
        for (int i = tid; i < 4096; i += 256) waggl[i] = wagg[i];
        for (int i = tid; i < 16 * 64; i += 256) {
            int er = i >> 6, j = i & 63;
            woutl[i] = wout[(size_t)(e0 + er) * 256 + 64 + j];
        }
        __syncthreads();
        for (int o = tid; o < 1024; o += 256) {
            int er = o >> 6, c = o & 63;
            float acc = 0.f;
#pragma unroll
            for (int j = 0; j < 64; j++) acc += woutl[er * 64 + j] * waggl[j * 64 + c];
            weff[(size_t)(e0 + er) * 256 + 64 + c] = f2bs(acc);
        }
        if (tid < 16) {
            float acc = 0.f;
            for (int j = 0; j < 64; j++) acc += a.bagg[j] * woutl[tid * 64 + j];
            a.bvec[e0 + tid] = acc;
        }
        return;
    }

    long long i = (long long)(blockIdx.x * 256 + threadIdx.x) * 8;
    const float* src; unsigned short* dst; long long rel;
    if (i < CSEG0)      { src = a.x;  dst = a.xb;  rel = i; }
    else if (i < CSEG1) { src = a.d0; dst = a.d0b; rel = i - CSEG0; }
    else if (i < CSEG2) { src = a.d1; dst = a.d1b; rel = i - CSEG1; }
    else {
        int widx = (int)(i - CSEG2);
#pragma unroll
        for (int k = 0; k < 8; k++) {
            int idx = widx + k;
            if (idx >= 233472) {
                int c = (idx - 233472) & 255;
                if (c >= 64 && c < 128) continue;   // fold blocks own these
            }
            const float* s; int r;
            if (idx < 131072)      { s = a.wp[idx >> 14]; r = idx & 16383; }
            else if (idx < 180224) { int q = idx - 131072; s = a.wp[8 + (q >> 14)]; r = q & 16383; }
            else if (idx < 229376) { int q = idx - 180224; s = a.wp[11 + (q >> 14)]; r = q & 16383; }
            else if (idx < 233472) { s = a.wp[14]; r = idx - 229376; }
            else                   { s = a.wp[15]; r = idx - 233472; }
            a.wb[idx] = f2bs(s[r]);
        }
        return;
    }
    float4 v0 = *(const float4*)(src + rel);
    float4 v1 = *(const float4*)(src + rel + 4);
    us8 o;
    o[0] = f2bs(v0.x); o[1] = f2bs(v0.y); o[2] = f2bs(v0.z); o[3] = f2bs(v0.w);
    o[4] = f2bs(v1.x); o[5] = f2bs(v1.y); o[6] = f2bs(v1.z); o[7] = f2bs(v1.w);
    *(us8*)(dst + rel) = o;
}

// ===========================================================================
// proj_all: blocks [0,768) = P-projection GEMM (128x128 tile);
//           blocks [768,984) = both dtw projections (128x64 tile).
// ===========================================================================
struct ProjArgs {
    const unsigned short *xb, *Wproj;
    const unsigned short *d0b, *d1b, *Wd0, *Wd1;
    unsigned short *P, *q0b, *q1b;
};

__global__ __launch_bounds__(256) void proj_all(ProjArgs pa)
{
    __shared__ unsigned short As[128 * 64];
    __shared__ unsigned short Ws[128 * 64];
    const int tid = threadIdx.x;
    const int lane = tid & 63;
    const int wid = tid >> 6;
    const int wm = wid >> 1, wn = wid & 1;
    const int l15 = lane & 15, l4 = lane >> 4;
    const int bid = blockIdx.x;

    if (bid < 768) {
        const int m0 = (bid % 192) * 128;
        const int e0 = (bid / 192) * 128;
        const unsigned short* A = pa.xb;
        const unsigned short* W = pa.Wproj;
        const int K = 256;

        f32x4 acc[4][4];
#pragma unroll
        for (int i = 0; i < 4; i++)
#pragma unroll
            for (int j = 0; j < 4; j++)
#pragma unroll
                for (int r = 0; r < 4; r++) acc[i][j][r] = 0.f;

        for (int kk = 0; kk < K; kk += 64) {
#pragma unroll
            for (int p = 0; p < 4; p++) {
                int off = p * 2048 + tid * 8;
                int r = off >> 6, cc = off & 63;
                GLOAD16(&A[(size_t)(m0 + r) * K + kk + cc], &As[p * 2048 + wid * 512]);
            }
#pragma unroll
            for (int p = 0; p < 4; p++) {
                int off = p * 2048 + tid * 8;
                int r = off >> 6, cc = off & 63;
                GLOAD16(&W[(size_t)(e0 + r) * K + kk + cc], &Ws[p * 2048 + wid * 512]);
            }
            __syncthreads();
#pragma unroll
            for (int ks = 0; ks < 64; ks += 32) {
                bf16x8 af[4], bw[4];
#pragma unroll
                for (int i = 0; i < 4; i++)
                    af[i] = *(bf16x8*)(&As[(wm * 64 + i * 16 + l15) * 64 + ks + l4 * 8]);
#pragma unroll
                for (int j = 0; j < 4; j++)
                    bw[j] = *(bf16x8*)(&Ws[(wn * 64 + j * 16 + l15) * 64 + ks + l4 * 8]);
#pragma unroll
                for (int i = 0; i < 4; i++)
#pragma unroll
                    for (int j = 0; j < 4; j++)
                        acc[i][j] = __builtin_amdgcn_mfma_f32_16x16x32_bf16(af[i], bw[j], acc[i][j], 0, 0, 0);
            }
            __syncthreads();
        }
#pragma unroll
        for (int i = 0; i < 4; i++)
#pragma unroll
            for (int j = 0; j < 4; j++) {
                int row0 = m0 + wm * 64 + i * 16 + l4 * 4;
                int col = e0 + wn * 64 + j * 16 + l15;
#pragma unroll
                for (int r = 0; r < 4; r++)
                    pa.P[(size_t)(row0 + r) * 512 + col] = f2bs(acc[i][j][r]);
            }
    } else {
        const int r0 = bid - 768;
        const int bx = r0 % 72, by = r0 / 72;
        const unsigned short *A, *W; unsigned short* O;
        int m0;
        if (bx < 24) { A = pa.d0b; W = pa.Wd0; O = pa.q0b; m0 = bx * 128; }
        else         { A = pa.d1b; W = pa.Wd1; O = pa.q1b; m0 = (bx - 24) * 128; }
        const int K = 256, ldo = 192;
        const int e0 = by * 64;

        f32x4 acc[4][2];
#pragma unroll
        for (int i = 0; i < 4; i++)
#pragma unroll
            for (int j = 0; j < 2; j++)
#pragma unroll
                for (int r = 0; r < 4; r++) acc[i][j][r] = 0.f;

        for (int kk = 0; kk < K; kk += 64) {
#pragma unroll
            for (int p = 0; p < 4; p++) {
                int off = p * 2048 + tid * 8;
                int r = off >> 6, cc = off & 63;
                GLOAD16(&A[(size_t)(m0 + r) * K + kk + cc], &As[p * 2048 + wid * 512]);
            }
#pragma unroll
            for (int p = 0; p < 2; p++) {
                int off = p * 2048 + tid * 8;
                int r = off >> 6, cc = off & 63;
                GLOAD16(&W[(size_t)(e0 + r) * K + kk + cc], &Ws[p * 2048 + wid * 512]);
            }
            __syncthreads();
#pragma unroll
            for (int ks = 0; ks < 64; ks += 32) {
                bf16x8 af[4], bw[2];
#pragma unroll
                for (int i = 0; i < 4; i++)
                    af[i] = *(bf16x8*)(&As[(wm * 64 + i * 16 + l15) * 64 + ks + l4 * 8]);
#pragma unroll
                for (int j = 0; j < 2; j++)
                    bw[j] = *(bf16x8*)(&Ws[(wn * 32 + j * 16 + l15) * 64 + ks + l4 * 8]);
#pragma unroll
                for (int i = 0; i < 4; i++)
#pragma unroll
                    for (int j = 0; j < 2; j++)
                        acc[i][j] = __builtin_amdgcn_mfma_f32_16x16x32_bf16(af[i], bw[j], acc[i][j], 0, 0, 0);
            }
            __syncthreads();
        }
#pragma unroll
        for (int i = 0; i < 4; i++)
#pragma unroll
            for (int j = 0; j < 2; j++) {
                int row0 = m0 + wm * 64 + i * 16 + l4 * 4;
                int col = e0 + wn * 32 + j * 16 + l15;
#pragma unroll
                for (int r = 0; r < 4; r++)
                    O[(size_t)(row0 + r) * ldo + col] = f2bs(acc[i][j][r]);
            }
    }
}

// ===========================================================================
// attn_all — balanced XCD swizzle + s_setprio(1) around MFMA clusters (T5).
// ===========================================================================
struct AttnArgs {
    const unsigned short* P;
    const unsigned short *qkv0, *qkv1;
    const float *map0, *map1;
    const float *lq1, *lk1, *lq2, *lk2, *subln;
    const float *tq, *ti;
    unsigned short* st;
};

#define BF16_ONE ((short)0x3F80)

template<int C>
__device__ inline void agg_phase64(
    const unsigned short* __restrict__ qkv, const float* __restrict__ cmap,
    unsigned short* SH, int bt, int h, int nq,
    int tid, int w, int l15, int g, float oacc[4])
{
    unsigned short* T  = SH;            // [64][136]
    unsigned short* Kf = SH + 8704;     // [C][40]
    unsigned short* Vt = SH + 13824;    // [16][136]
    unsigned short* QT = SH + 16000;    // [16][136]
    unsigned short* Qb = SH + 18176;    // [64][40]

    for (int i = tid; i < 64 * (C / 8); i += 256) {
        int nn = i & 63, c0 = i >> 6;
        us8 v;
#pragma unroll
        for (int j = 0; j < 8; j++)
            v[j] = f2bs_r(cmap[(size_t)(c0 * 8 + j) * 512 + nq * 64 + nn]);
        *(us8*)&T[nn * 136 + c0 * 8] = v;
    }
    const us8 z8 = {0, 0, 0, 0, 0, 0, 0, 0};
    for (int i = tid; i < C * 2; i += 256) {
        int c = i >> 1, hf = i & 1;
        const unsigned short* base = qkv + ((size_t)(bt * C + c)) * 192 + h * 16 + hf * 8;
        us8 qv = *(const us8*)(base);
        us8 kv = *(const us8*)(base + 64);
        us8 vv = *(const us8*)(base + 128);
        *(us8*)&Kf[c * 40 + hf * 8] = kv;
        *(us8*)&Kf[c * 40 + 16 + hf * 8] = z8;
#pragma unroll
        for (int e = 0; e < 8; e++) {
            QT[(hf * 8 + e) * 136 + c] = qv[e];
            Vt[(hf * 8 + e) * 136 + c] = vv[e];
        }
    }
    __syncthreads();

    const f32x4 z4 = {0.f, 0.f, 0.f, 0.f};
    f32x4 qac = z4;
    __builtin_amdgcn_s_setprio(1);
    for (int kk = 0; kk < C; kk += 32) {
        bf16x8 bwq = *(bf16x8*)&QT[l15 * 136 + kk + g * 8];
        bf16x8 af = *(bf16x8*)&T[(w * 16 + l15) * 136 + kk + g * 8];
        qac = __builtin_amdgcn_mfma_f32_16x16x32_bf16(af, bwq, qac, 0, 0, 0);
    }
    __builtin_amdgcn_s_setprio(0);
    const float qs = SCALE_H * LOG2E;
#pragma unroll
    for (int r = 0; r < 4; r++) {
        int row = w * 16 + g * 4 + r;
        Qb[row * 40 + l15] = f2bs_r(qac[r] * qs);
        Qb[row * 40 + 16 + l15] = 0;
    }
    __syncthreads();   // T reads done; alias as P-bounce

    unsigned short* Pl = SH;   // [64][40] aliases T
    const bf16x8 onesb = {BF16_ONE, BF16_ONE, BF16_ONE, BF16_ONE,
                          BF16_ONE, BF16_ONE, BF16_ONE, BF16_ONE};
    f32x4 O = z4;
    f32x4 R = z4;   // MFMA row-sums

    for (int mc = 0; mc < C; mc += 32) {
        bf16x8 kva = *(bf16x8*)&Kf[(mc + l15) * 40 + g * 8];
        bf16x8 kvb = *(bf16x8*)&Kf[(mc + 16 + l15) * 40 + g * 8];
        bf16x8 vf  = *(bf16x8*)&Vt[l15 * 136 + mc + g * 8];
        bf16x8 qf2 = *(bf16x8*)&Qb[(w * 16 + l15) * 40 + g * 8];
        __builtin_amdgcn_s_setprio(1);
        f32x4 sa = __builtin_amdgcn_mfma_f32_16x16x32_bf16(kva, qf2, z4, 0, 0, 0);
        f32x4 sb = __builtin_amdgcn_mfma_f32_16x16x32_bf16(kvb, qf2, z4, 0, 0, 0);
        __builtin_amdgcn_s_setprio(0);
        us4 wa, wb2;
#pragma unroll
        for (int r = 0; r < 4; r++) {
            wa[r]  = f2bs_r(__builtin_amdgcn_exp2f(sa[r]));
            wb2[r] = f2bs_r(__builtin_amdgcn_exp2f(sb[r]));
        }
        *(us4*)&Pl[(w * 16 + l15) * 40 + g * 4] = wa;
        *(us4*)&Pl[(w * 16 + l15) * 40 + 16 + g * 4] = wb2;

        bf16x8 pf = *(bf16x8*)&Pl[(w * 16 + l15) * 40 + g * 8];
        __builtin_amdgcn_s_setprio(1);
        O = __builtin_amdgcn_mfma_f32_16x16x32_bf16(pf, vf, O, 0, 0, 0);
        R = __builtin_amdgcn_mfma_f32_16x16x32_bf16(pf, onesb, R, 0, 0, 0);
        __builtin_amdgcn_s_setprio(0);
    }

#pragma unroll
    for (int r = 0; r < 4; r++)
        oacc[r] += O[r] / R[r];
    __syncthreads();
}

__global__ __launch_bounds__(256) void attn_all(AttnArgs aa)
{
    __shared__ unsigned short SH[25728];   // 51456 B union
    // Per-branch balanced XCD swizzle (hw -> logical).
    const int hw = blockIdx.x;
    int bid;
    if (hw < 768) {
        int m = hw & 7, s = hw >> 3;            // s in [0,96)
        bid = (m * 24 + (s >> 2)) * 4 + (s & 3);
    } else if (hw < 2304) {
        int r = hw - 768;
        int m = r & 7, s = r >> 3;              // s in [0,192)
        bid = 768 + (m * 24 + (s >> 3)) * 8 + (s & 7);
    } else {
        bid = hw;
    }
    const int tid = threadIdx.x;
    const int lane = tid & 63, w = tid >> 6;
    const int l15 = lane & 15, g = lane >> 4;

    if (bid < 768) {
        // ================= spatial differential attention =================
        unsigned short* Kl = SH;            // [512][24] = 12288 us
        unsigned short* Vt = SH + 12288;    // [16][520] =  8320 us
        unsigned short* Pl = SH + 20608;    // [4][32][40] = 5120 us
        const unsigned short* P = aa.P;

        const int bth = bid >> 2, qc = bid & 3;
        const int h = bth & 3, bt = bth >> 2;

        const unsigned short* kbase = P + (size_t)bt * N_ * 512 + 64 + h * 16;
        const unsigned short* vbase = P + (size_t)bt * N_ * 512 + 128 + h * 16;
        const float kscale = SCALE_S * LOG2E;
        for (int i = tid; i < 512; i += 256) {
            us8 k0 = *(const us8*)(kbase + (size_t)i * 512);
            us8 k1 = *(const us8*)(kbase + (size_t)i * 512 + 8);
            us8 s0, s1;
#pragma unroll
            for (int r = 0; r < 8; r++) {
                s0[r] = f2bs_r(b2f(k0[r]) * kscale);
                s1[r] = f2bs_r(b2f(k1[r]) * kscale);
            }
            *(us8*)&Kl[i * 24] = s0;
            *(us8*)&Kl[i * 24 + 8] = s1;
            us8 v0 = *(const us8*)(vbase + (size_t)i * 512);
            us8 v1 = *(const us8*)(vbase + (size_t)i * 512 + 8);
#pragma unroll
            for (int e = 0; e < 8; e++) { Vt[e * 520 + i] = v0[e]; Vt[(8 + e) * 520 + i] = v1[e]; }
        }
        __syncthreads();

        float e1 = 0.f, e2 = 0.f;
#pragma unroll
        for (int j = 0; j < 8; j++) { e1 += aa.lq1[j] * aa.lk1[j]; e2 += aa.lq2[j] * aa.lk2[j]; }
        const float lam = __expf(e1) - __expf(e2) + LAMBDA_INIT;

        const int q0 = qc * 128 + w * 32;

        bf16x8 qf[2];
#pragma unroll
        for (int qt = 0; qt < 2; qt++)
            qf[qt] = *(const bf16x8*)(P + ((size_t)bt * N_ + q0 + qt * 16 + l15) * 512 + h * 16 + (g & 1) * 8);

        const f32x4 z4 = {0.f, 0.f, 0.f, 0.f};
        const bf16x8 zb = {0, 0, 0, 0, 0, 0, 0, 0};
        const bf16x8 onesb = {BF16_ONE, BF16_ONE, BF16_ONE, BF16_ONE,
                              BF16_ONE, BF16_ONE, BF16_ONE, BF16_ONE};
        f32x4 O1[2], O2[2], R1[2], R2[2];
#pragma unroll
        for (int qt = 0; qt < 2; qt++)
#pragma unroll
            for (int r = 0; r < 4; r++) {
                O1[qt][r] = 0.f; O2[qt][r] = 0.f;
                R1[qt][r] = 0.f; R2[qt][r] = 0.f;
            }

        for (int mc = 0; mc < 512; mc += 32) {
            bf16x8 kva = *(bf16x8*)&Kl[(mc + l15) * 24 + (g & 1) * 8];
            bf16x8 kvb = *(bf16x8*)&Kl[(mc + 16 + l15) * 24 + (g & 1) * 8];
            bf16x8 a1a = (g == 0) ? kva : zb, a2a = (g == 1) ? kva : zb;
            bf16x8 a1b = (g == 0) ? kvb : zb, a2b = (g == 1) ? kvb : zb;
            bf16x8 vf = *(bf16x8*)&Vt[l15 * 520 + mc + g * 8];

            f32x4 s1a[2], s1b[2], s2a[2], s2b[2];
            __builtin_amdgcn_s_setprio(1);
#pragma unroll
            for (int qt = 0; qt < 2; qt++) {
                s1a[qt] = __builtin_amdgcn_mfma_f32_16x16x32_bf16(a1a, qf[qt], z4, 0, 0, 0);
                s1b[qt] = __builtin_amdgcn_mfma_f32_16x16x32_bf16(a1b, qf[qt], z4, 0, 0, 0);
                s2a[qt] = __builtin_amdgcn_mfma_f32_16x16x32_bf16(a2a, qf[qt], z4, 0, 0, 0);
                s2b[qt] = __builtin_amdgcn_mfma_f32_16x16x32_bf16(a2b, qf[qt], z4, 0, 0, 0);
            }
            __builtin_amdgcn_s_setprio(0);

#pragma unroll
            for (int qt = 0; qt < 2; qt++) {
                us4 w0, w1;
#pragma unroll
                for (int r = 0; r < 4; r++) {
                    w0[r] = f2bs_r(__builtin_amdgcn_exp2f(s1a[qt][r]));
                    w1[r] = f2bs_r(__builtin_amdgcn_exp2f(s1b[qt][r]));
                }
                *(us4*)&Pl[(w * 32 + qt * 16 + l15) * 40 + g * 4] = w0;
                *(us4*)&Pl[(w * 32 + qt * 16 + l15) * 40 + 16 + g * 4] = w1;
            }
            __builtin_amdgcn_s_setprio(1);
#pragma unroll
            for (int qt = 0; qt < 2; qt++) {
                bf16x8 pf = *(bf16x8*)&Pl[(w * 32 + qt * 16 + l15) * 40 + g * 8];
                O1[qt] = __builtin_amdgcn_mfma_f32_16x16x32_bf16(pf, vf, O1[qt], 0, 0, 0);
                R1[qt] = __builtin_amdgcn_mfma_f32_16x16x32_bf16(pf, onesb, R1[qt], 0, 0, 0);
            }
            __builtin_amdgcn_s_setprio(0);
#pragma unroll
            for (int qt = 0; qt < 2; qt++) {
                us4 w0, w1;
#pragma unroll
                for (int r = 0; r < 4; r++) {
                    w0[r] = f2bs_r(__builtin_amdgcn_exp2f(s2a[qt][r]));
                    w1[r] = f2bs_r(__builtin_amdgcn_exp2f(s2b[qt][r]));
                }
                *(us4*)&Pl[(w * 32 + qt * 16 + l15) * 40 + g * 4] = w0;
                *(us4*)&Pl[(w * 32 + qt * 16 + l15) * 40 + 16 + g * 4] = w1;
            }
            __builtin_amdgcn_s_setprio(1);
#pragma unroll
            for (int qt = 0; qt < 2; qt++) {
                bf16x8 pf = *(bf16x8*)&Pl[(w * 32 + qt * 16 + l15) * 40 + g * 8];
                O2[qt] = __builtin_amdgcn_mfma_f32_16x16x32_bf16(pf, vf, O2[qt], 0, 0, 0);
                R2[qt] = __builtin_amdgcn_mfma_f32_16x16x32_bf16(pf, onesb, R2[qt], 0, 0, 0);
            }
            __builtin_amdgcn_s_setprio(0);
        }

        const float sw = aa.subln[l15];
#pragma unroll
        for (int qt = 0; qt < 2; qt++) {
#pragma unroll
            for (int r = 0; r < 4; r++) {
                int qrow = g * 4 + r;
                float o = O1[qt][r] / R1[qt][r] - lam * (O2[qt][r] / R2[qt][r]);
                float ss = o * o;
                ss += __shfl_xor(ss, 1); ss += __shfl_xor(ss, 2);
                ss += __shfl_xor(ss, 4); ss += __shfl_xor(ss, 8);
                float rms = rsqrtf(ss * (1.0f / 16.0f) + EPS_);
                float val = 0.8f * o * rms * sw;
                int q = q0 + qt * 16 + qrow;
                aa.st[((size_t)bt * N_ + q) * 256 + h * 16 + l15] = f2bs_r(val);
            }
        }
    } else if (bid < 2304) {
        // ======== dtw-aggregated spatial attention (64-row n-chunks) ========
        const int r0 = bid - 768;           // [0,1536)
        const int bth = r0 >> 3, nq = r0 & 7;
        const int h = bth & 3, bt = bth >> 2;

        float oacc[4] = {};
        agg_phase64<64>(aa.qkv0, aa.map0, SH, bt, h, nq, tid, w, l15, g, oacc);
        agg_phase64<128>(aa.qkv1, aa.map1, SH, bt, h, nq, tid, w, l15, g, oacc);

#pragma unroll
        for (int r = 0; r < 4; r++) {
            int n = nq * 64 + w * 16 + g * 4 + r;
            aa.st[((size_t)(bt * N_ + n)) * 256 + 64 + h * 16 + l15] = f2bs_r(oacc[r]);
        }
    } else {
        // ========== temporal + agg-temporal (2 n per 256-thr block) ==========
        const int r0 = bid - 2304;          // [0,1024)
        const int flat = r0 * 2;
        const int b = flat >> 9;
        const int n0 = flat & 511;
        const int p = tid >> 7;             // which n
        const int t127 = tid & 127;
        const int n = n0 + p;
        unsigned short* Pt = SH + p * (T_ * 328);   // [12][328]
        const unsigned short* P = aa.P;

        for (int i = t127; i < T_ * 40; i += 128) {
            int u = i / 40, c8 = i % 40;
            *(us8*)&Pt[u * 328 + c8 * 8] =
                *(const us8*)(P + (((size_t)(b * T_ + u) * N_) + n) * 512 + 192 + c8 * 8);
        }
        __syncthreads();

        if (t127 < 96) {
            const int part = t127 / 48;
            const int rem = t127 % 48;
            const int h = rem / T_, t = rem % T_;

            float q[16];
            if (!part) {
                us8 a0 = *(const us8*)&Pt[t * 328 + h * 16];
                us8 bq = *(const us8*)&Pt[t * 328 + h * 16 + 8];
#pragma unroll
                for (int f = 0; f < 8; f++) { q[f] = b2f(a0[f]); q[8 + f] = b2f(bq[f]); }
            } else {
                float wseg[SEG_];
#pragma unroll
                for (int s = 0; s < SEG_; s++)
                    wseg[s] = aa.ti[(((size_t)b * N_ + n) * T_ + t) * SEG_ + s];
#pragma unroll
                for (int f = 0; f < 16; f++) q[f] = 0.f;
                for (int s = 0; s < SEG_; s++) {
                    const float* qa = aa.tq + ((size_t)n * SEG_ + s) * 64 + h * 16;
#pragma unroll
                    for (int f = 0; f < 16; f++) q[f] += wseg[s] * qa[f];
                }
            }
            const int kc = part ? 192 : 64;
            const int vc = part ? 256 : 128;

            float sc[T_]; float mx = -1e30f;
            for (int u = 0; u < T_; u++) {
                us8 a0 = *(const us8*)&Pt[u * 328 + kc + h * 16];
                us8 bk = *(const us8*)&Pt[u * 328 + kc + h * 16 + 8];
                float s = 0.f;
#pragma unroll
                for (int f = 0; f < 8; f++) s += q[f] * b2f(a0[f]) + q[8 + f] * b2f(bk[f]);
                s *= SCALE_H;
                sc[u] = s; mx = fmaxf(mx, s);
            }
            float sum = 0.f;
            for (int u = 0; u < T_; u++) { sc[u] = __expf(sc[u] - mx); sum += sc[u]; }
            float inv = 1.0f / sum;
            float o[16] = {};
            for (int u = 0; u < T_; u++) {
                us8 a0 = *(const us8*)&Pt[u * 328 + vc + h * 16];
                us8 bv = *(const us8*)&Pt[u * 328 + vc + h * 16 + 8];
                float ww = sc[u] * inv;
#pragma unroll
                for (int f = 0; f < 8; f++) { o[f] += ww * b2f(a0[f]); o[8 + f] += ww * b2f(bv[f]); }
            }
            unsigned short* orow = aa.st + (((size_t)(b * T_ + t) * N_) + n) * 256 + (part ? 192 : 128) + h * 16;
            us8 w0, w1;
#pragma unroll
            for (int f = 0; f < 8; f++) { w0[f] = f2bs_r(o[f]); w1[f] = f2bs_r(o[8 + f]); }
            *(us8*)orow = w0;
            *(us8*)(orow + 8) = w1;
        }
    }
}

// ===========================================================================
// Output projection (128x128 tile), fp32 out, bias = folded b_agg.
// ===========================================================================
__global__ __launch_bounds__(256) void out_proj(
    const unsigned short* __restrict__ A, const unsigned short* __restrict__ W,
    const float* __restrict__ bias, float* __restrict__ O)
{
    __shared__ unsigned short As[128 * 64];
    __shared__ unsigned short Ws[128 * 64];
    const int m0 = blockIdx.x * 128;
    const int e0 = blockIdx.y * 128;
    const int tid = threadIdx.x;
    const int lane = tid & 63;
    const int wid = tid >> 6;
    const int wm = wid >> 1, wn = wid & 1;
    const int l15 = lane & 15, l4 = lane >> 4;
    const int K = 256;

    f32x4 acc[4][4];
#pragma unroll
    for (int i = 0; i < 4; i++)
#pragma unroll
        for (int j = 0; j < 4; j++)
#pragma unroll
            for (int r = 0; r < 4; r++) acc[i][j][r] = 0.f;

    for (int kk = 0; kk < K; kk += 64) {
#pragma unroll
        for (int p = 0; p < 4; p++) {
            int off = p * 2048 + tid * 8;
            int r = off >> 6, cc = off & 63;
            GLOAD16(&A[(size_t)(m0 + r) * K + kk + cc], &As[p * 2048 + wid * 512]);
        }
#pragma unroll
        for (int p = 0; p < 4; p++) {
            int off = p * 2048 + tid * 8;
            int r = off >> 6, cc = off & 63;
            GLOAD16(&W[(size_t)(e0 + r) * K + kk + cc], &Ws[p * 2048 + wid * 512]);
        }
        __syncthreads();
#pragma unroll
        for (int ks = 0; ks < 64; ks += 32) {
            bf16x8 af[4], bw[4];
#pragma unroll
            for (int i = 0; i < 4; i++)
                af[i] = *(bf16x8*)(&As[(wm * 64 + i * 16 + l15) * 64 + ks + l4 * 8]);
#pragma unroll
            for (int j = 0; j < 4; j++)
                bw[j] = *(bf16x8*)(&Ws[(wn * 64 + j * 16 + l15) * 64 + ks + l4 * 8]);
#pragma unroll
            for (int i = 0; i < 4; i++)
#pragma unroll
                for (int j = 0; j < 4; j++)
                    acc[i][j] = __builtin_amdgcn_mfma_f32_16x16x32_bf16(af[i], bw[j], acc[i][j], 0, 0, 0);
        }
        __syncthreads();
    }

#pragma unroll
    for (int i = 0; i < 4; i++)
#pragma unroll
        for (int j = 0; j < 4; j++) {
            int row0 = m0 + wm * 64 + i * 16 + l4 * 4;
            int col = e0 + wn * 64 + j * 16 + l15;
            float bv = bias[col];
#pragma unroll
            for (int r = 0; r < 4; r++)
                O[(size_t)(row0 + r) * 256 + col] = acc[i][j][r] + bv;
        }
}

// ===========================================================================
extern "C" void kernel_launch(void* const* d_in, const int* in_sizes, int n_in,
                              void* d_out, int out_size, void* d_ws, size_t ws_size,
                              hipStream_t stream)
{
    const float* x      = (const float*)d_in[0];
    const float* dtw0   = (const float*)d_in[1];
    const float* dtw1   = (const float*)d_in[2];
    const float* map0   = (const float*)d_in[3];
    const float* map1   = (const float*)d_in[4];
    const float* tmpinf = (const float*)d_in[5];
    const float* lq1    = (const float*)d_in[9];
    const float* lk1    = (const float*)d_in[10];
    const float* lq2    = (const float*)d_in[11];
    const float* lk2    = (const float*)d_in[12];
    const float* subln  = (const float*)d_in[13];
    const float* Wagg_f = (const float*)d_in[20];
    const float* b_agg  = (const float*)d_in[21];
    const float* tq     = (const float*)d_in[25];
    const float* Wout_f = (const float*)d_in[28];
    float* out = (float*)d_out;

    const size_t M = (size_t)BT_ * N_;   // 24576

    char* w = (char*)d_ws;
    unsigned short* P     = (unsigned short*)w;   w += M * 512 * 2;
    unsigned short* st    = (unsigned short*)w;   w += M * 256 * 2;
    unsigned short* qkv0b = (unsigned short*)w;   w += (size_t)BT_ * 64 * 192 * 2;
    unsigned short* qkv1b = (unsigned short*)w;   w += (size_t)BT_ * 128 * 192 * 2;
    unsigned short* xb    = (unsigned short*)w;   w += M * 256 * 2;
    unsigned short* d0b   = (unsigned short*)w;   w += (size_t)BT_ * 64 * 256 * 2;
    unsigned short* d1b   = (unsigned short*)w;   w += (size_t)BT_ * 128 * 256 * 2;
    unsigned short* wb    = (unsigned short*)w;   w += 299008 * 2;
    float*          bvec  = (float*)w;            w += 256 * 4;

    unsigned short* Wproj = wb;
    unsigned short* Wd0   = wb + 131072;
    unsigned short* Wd1   = wb + 180224;
    unsigned short* Weff  = wb + 233472;

    dim3 blk(256);

    // 1. conversions + Wagg fold (disjoint writes within one launch)
    ConvArgs ca;
    ca.x = x; ca.d0 = dtw0; ca.d1 = dtw1;
    ca.wp[0] = (const float*)d_in[6];  ca.wp[1] = (const float*)d_in[7];  ca.wp[2] = (const float*)d_in[8];
    ca.wp[3] = (const float*)d_in[22]; ca.wp[4] = (const float*)d_in[23]; ca.wp[5] = (const float*)d_in[24];
    ca.wp[6] = (const float*)d_in[26]; ca.wp[7] = (const float*)d_in[27];
    ca.wp[8] = (const float*)d_in[14]; ca.wp[9] = (const float*)d_in[15]; ca.wp[10] = (const float*)d_in[16];
    ca.wp[11] = (const float*)d_in[17]; ca.wp[12] = (const float*)d_in[18]; ca.wp[13] = (const float*)d_in[19];
    ca.wp[14] = Wagg_f; ca.wp[15] = Wout_f;
    ca.bagg = b_agg;
    ca.xb = xb; ca.d0b = d0b; ca.d1b = d1b; ca.wb = wb; ca.bvec = bvec;
    hipLaunchKernelGGL(prep_all, dim3(NCONVBLK + 16), blk, 0, stream, ca);

    // 2. all projections (P + dtw) in one launch
    ProjArgs pa;
    pa.xb = xb; pa.Wproj = Wproj;
    pa.d0b = d0b; pa.d1b = d1b; pa.Wd0 = Wd0; pa.Wd1 = Wd1;
    pa.P = P; pa.q0b = qkv0b; pa.q1b = qkv1b;
    hipLaunchKernelGGL(proj_all, dim3(984), blk, 0, stream, pa);

    // 3. all attention branches in one launch (balanced XCD swizzle)
    AttnArgs aa;
    aa.P = P; aa.qkv0 = qkv0b; aa.qkv1 = qkv1b;
    aa.map0 = map0; aa.map1 = map1;
    aa.lq1 = lq1; aa.lk1 = lk1; aa.lq2 = lq2; aa.lk2 = lk2; aa.subln = subln;
    aa.tq = tq; aa.ti = tmpinf; aa.st = st;
    hipLaunchKernelGGL(attn_all, dim3(3328), blk, 0, stream, aa);

    // 4. output projection
    hipLaunchKernelGGL(out_proj, dim3(192, 2), blk, 0, stream,
                       st, Weff, bvec, out);
}

// Round 18
// 90.008 us; speedup vs baseline: 1.0022x; 1.0022x over previous
//
#include <hip/hip_runtime.h>
#include <hip/hip_bf16.h>
#include <cstddef>

#define B_ 4
#define T_ 12
#define N_ 512
#define D_ 256
#define H_ 4
#define SEG_ 6
#define BT_ (B_*T_)

#define SCALE_S 0.35355339059327373f   /* 8^-0.5  */
#define SCALE_H 0.25f                  /* 16^-0.5 */
#define LOG2E   1.44269504088896340736f
#define LAMBDA_INIT 0.2f
#define EPS_ 1e-6f

typedef short bf16x8 __attribute__((ext_vector_type(8)));
typedef float f32x4 __attribute__((ext_vector_type(4)));
typedef unsigned short us8 __attribute__((ext_vector_type(8)));
typedef unsigned short us4 __attribute__((ext_vector_type(4)));

__device__ inline float b2f(unsigned short u) {
    union { unsigned int i; float f; } x; x.i = ((unsigned int)u) << 16; return x.f;
}
// library convert (RNE + NaN handling) — prep only
__device__ inline unsigned short f2bs(float f) {
    __hip_bfloat16 b = __float2bfloat16(f);
    return *(unsigned short*)&b;
}
// fast 2-op bf16 pack (round-half-up; finite values) — hot loops
__device__ inline unsigned short f2bs_r(float f) {
    union { float f; unsigned int u; } x; x.f = f;
    return (unsigned short)((x.u + 0x8000u) >> 16);
}

#define GLOAD16(gsrc, ldst) \
    __builtin_amdgcn_global_load_lds((const __attribute__((address_space(1))) void*)(gsrc), \
                                     (__attribute__((address_space(3))) void*)(ldst), 16, 0, 0)

// ===========================================================================
// prep_all: blocks [0,4370) = fp32->bf16 conversions;
//           blocks [4370,4386) = Wagg fold into Weff cols [64,128) + bvec.
// Conv branch SKIPS Weff cols [64,128) — fold blocks are the sole writers.
// ===========================================================================
struct ConvArgs {
    const float* x; const float* d0; const float* d1;
    const float* wp[16];
    const float* bagg;
    unsigned short* xb; unsigned short* d0b; unsigned short* d1b; unsigned short* wb;
    float* bvec;
};
#define CSEG0 6291456
#define CSEG1 (CSEG0 + 786432)
#define CSEG2 (CSEG1 + 1572864)
#define CTOT  (CSEG2 + 299008)
#define NCONVBLK 4370   /* CTOT/8/256 */

__global__ __launch_bounds__(256) void prep_all(ConvArgs a)
{
    __shared__ float waggl[64 * 64];
    __shared__ float woutl[16 * 64];

    if (blockIdx.x >= NCONVBLK) {
        const float* wout = a.wp[15];
        const float* wagg = a.wp[14];
        unsigned short* weff = a.wb + 233472;
        const int tid = threadIdx.x;
        const int e0 = (blockIdx.x - NCONVBLK) * 16;
        for (int i = tid; i < 4096; i += 256) waggl[i] = wagg[i];
        for (int i = tid; i < 16 * 64; i += 256) {
            int er = i >> 6, j = i & 63;
            woutl[i] = wout[(size_t)(e0 + er) * 256 + 64 + j];
        }
        __syncthreads();
        for (int o = tid; o < 1024; o += 256) {
            int er = o >> 6, c = o & 63;
            float acc = 0.f;
#pragma unroll
            for (int j = 0; j < 64; j++) acc += woutl[er * 64 + j] * waggl[j * 64 + c];
            weff[(size_t)(e0 + er) * 256 + 64 + c] = f2bs(acc);
        }
        if (tid < 16) {
            float acc = 0.f;
            for (int j = 0; j < 64; j++) acc += a.bagg[j] * woutl[tid * 64 + j];
            a.bvec[e0 + tid] = acc;
        }
        return;
    }

    long long i = (long long)(blockIdx.x * 256 + threadIdx.x) * 8;
    const float* src; unsigned short* dst; long long rel;
    if (i < CSEG0)      { src = a.x;  dst = a.xb;  rel = i; }
    else if (i < CSEG1) { src = a.d0; dst = a.d0b; rel = i - CSEG0; }
    else if (i < CSEG2) { src = a.d1; dst = a.d1b; rel = i - CSEG1; }
    else {
        int widx = (int)(i - CSEG2);
#pragma unroll
        for (int k = 0; k < 8; k++) {
            int idx = widx + k;
            if (idx >= 233472) {
                int c = (idx - 233472) & 255;
                if (c >= 64 && c < 128) continue;   // fold blocks own these
            }
            const float* s; int r;
            if (idx < 131072)      { s = a.wp[idx >> 14]; r = idx & 16383; }
            else if (idx < 180224) { int q = idx - 131072; s = a.wp[8 + (q >> 14)]; r = q & 16383; }
            else if (idx < 229376) { int q = idx - 180224; s = a.wp[11 + (q >> 14)]; r = q & 16383; }
            else if (idx < 233472) { s = a.wp[14]; r = idx - 229376; }
            else                   { s = a.wp[15]; r = idx - 233472; }
            a.wb[idx] = f2bs(s[r]);
        }
        return;
    }
    float4 v0 = *(const float4*)(src + rel);
    float4 v1 = *(const float4*)(src + rel + 4);
    us8 o;
    o[0] = f2bs(v0.x); o[1] = f2bs(v0.y); o[2] = f2bs(v0.z); o[3] = f2bs(v0.w);
    o[4] = f2bs(v1.x); o[5] = f2bs(v1.y); o[6] = f2bs(v1.z); o[7] = f2bs(v1.w);
    *(us8*)(dst + rel) = o;
}

// ===========================================================================
// proj_all: blocks [0,768) = P-projection GEMM (128x128 tile);
//           blocks [768,984) = both dtw projections (128x64 tile).
// ===========================================================================
struct ProjArgs {
    const unsigned short *xb, *Wproj;
    const unsigned short *d0b, *d1b, *Wd0, *Wd1;
    unsigned short *P, *q0b, *q1b;
};

__global__ __launch_bounds__(256) void proj_all(ProjArgs pa)
{
    __shared__ unsigned short As[128 * 64];
    __shared__ unsigned short Ws[128 * 64];
    const int tid = threadIdx.x;
    const int lane = tid & 63;
    const int wid = tid >> 6;
    const int wm = wid >> 1, wn = wid & 1;
    const int l15 = lane & 15, l4 = lane >> 4;
    const int bid = blockIdx.x;

    if (bid < 768) {
        const int m0 = (bid % 192) * 128;
        const int e0 = (bid / 192) * 128;
        const unsigned short* A = pa.xb;
        const unsigned short* W = pa.Wproj;
        const int K = 256;

        f32x4 acc[4][4];
#pragma unroll
        for (int i = 0; i < 4; i++)
#pragma unroll
            for (int j = 0; j < 4; j++)
#pragma unroll
                for (int r = 0; r < 4; r++) acc[i][j][r] = 0.f;

        for (int kk = 0; kk < K; kk += 64) {
#pragma unroll
            for (int p = 0; p < 4; p++) {
                int off = p * 2048 + tid * 8;
                int r = off >> 6, cc = off & 63;
                GLOAD16(&A[(size_t)(m0 + r) * K + kk + cc], &As[p * 2048 + wid * 512]);
            }
#pragma unroll
            for (int p = 0; p < 4; p++) {
                int off = p * 2048 + tid * 8;
                int r = off >> 6, cc = off & 63;
                GLOAD16(&W[(size_t)(e0 + r) * K + kk + cc], &Ws[p * 2048 + wid * 512]);
            }
            __syncthreads();
#pragma unroll
            for (int ks = 0; ks < 64; ks += 32) {
                bf16x8 af[4], bw[4];
#pragma unroll
                for (int i = 0; i < 4; i++)
                    af[i] = *(bf16x8*)(&As[(wm * 64 + i * 16 + l15) * 64 + ks + l4 * 8]);
#pragma unroll
                for (int j = 0; j < 4; j++)
                    bw[j] = *(bf16x8*)(&Ws[(wn * 64 + j * 16 + l15) * 64 + ks + l4 * 8]);
#pragma unroll
                for (int i = 0; i < 4; i++)
#pragma unroll
                    for (int j = 0; j < 4; j++)
                        acc[i][j] = __builtin_amdgcn_mfma_f32_16x16x32_bf16(af[i], bw[j], acc[i][j], 0, 0, 0);
            }
            __syncthreads();
        }
#pragma unroll
        for (int i = 0; i < 4; i++)
#pragma unroll
            for (int j = 0; j < 4; j++) {
                int row0 = m0 + wm * 64 + i * 16 + l4 * 4;
                int col = e0 + wn * 64 + j * 16 + l15;
#pragma unroll
                for (int r = 0; r < 4; r++)
                    pa.P[(size_t)(row0 + r) * 512 + col] = f2bs(acc[i][j][r]);
            }
    } else {
        const int r0 = bid - 768;
        const int bx = r0 % 72, by = r0 / 72;
        const unsigned short *A, *W; unsigned short* O;
        int m0;
        if (bx < 24) { A = pa.d0b; W = pa.Wd0; O = pa.q0b; m0 = bx * 128; }
        else         { A = pa.d1b; W = pa.Wd1; O = pa.q1b; m0 = (bx - 24) * 128; }
        const int K = 256, ldo = 192;
        const int e0 = by * 64;

        f32x4 acc[4][2];
#pragma unroll
        for (int i = 0; i < 4; i++)
#pragma unroll
            for (int j = 0; j < 2; j++)
#pragma unroll
                for (int r = 0; r < 4; r++) acc[i][j][r] = 0.f;

        for (int kk = 0; kk < K; kk += 64) {
#pragma unroll
            for (int p = 0; p < 4; p++) {
                int off = p * 2048 + tid * 8;
                int r = off >> 6, cc = off & 63;
                GLOAD16(&A[(size_t)(m0 + r) * K + kk + cc], &As[p * 2048 + wid * 512]);
            }
#pragma unroll
            for (int p = 0; p < 2; p++) {
                int off = p * 2048 + tid * 8;
                int r = off >> 6, cc = off & 63;
                GLOAD16(&W[(size_t)(e0 + r) * K + kk + cc], &Ws[p * 2048 + wid * 512]);
            }
            __syncthreads();
#pragma unroll
            for (int ks = 0; ks < 64; ks += 32) {
                bf16x8 af[4], bw[2];
#pragma unroll
                for (int i = 0; i < 4; i++)
                    af[i] = *(bf16x8*)(&As[(wm * 64 + i * 16 + l15) * 64 + ks + l4 * 8]);
#pragma unroll
                for (int j = 0; j < 2; j++)
                    bw[j] = *(bf16x8*)(&Ws[(wn * 32 + j * 16 + l15) * 64 + ks + l4 * 8]);
#pragma unroll
                for (int i = 0; i < 4; i++)
#pragma unroll
                    for (int j = 0; j < 2; j++)
                        acc[i][j] = __builtin_amdgcn_mfma_f32_16x16x32_bf16(af[i], bw[j], acc[i][j], 0, 0, 0);
            }
            __syncthreads();
        }
#pragma unroll
        for (int i = 0; i < 4; i++)
#pragma unroll
            for (int j = 0; j < 2; j++) {
                int row0 = m0 + wm * 64 + i * 16 + l4 * 4;
                int col = e0 + wn * 32 + j * 16 + l15;
#pragma unroll
                for (int r = 0; r < 4; r++)
                    O[(size_t)(row0 + r) * ldo + col] = f2bs(acc[i][j][r]);
            }
    }
}

// ===========================================================================
// attn_all — balanced XCD swizzle; LDS union shrunk to 38144 B for 4 blk/CU:
//   spatial: Kl [512][16] (was 24), Pl [4][16][40] (qt-sequenced, was x32),
//   agg: masked-lane zeros (Kf [C][24], Qb [64][24], no stored zeros).
// ===========================================================================
struct AttnArgs {
    const unsigned short* P;
    const unsigned short *qkv0, *qkv1;
    const float *map0, *map1;
    const float *lq1, *lk1, *lq2, *lk2, *subln;
    const float *tq, *ti;
    unsigned short* st;
};

#define BF16_ONE ((short)0x3F80)

template<int C>
__device__ inline void agg_phase64(
    const unsigned short* __restrict__ qkv, const float* __restrict__ cmap,
    unsigned short* SH, int bt, int h, int nq,
    int tid, int w, int l15, int g, float oacc[4])
{
    unsigned short* T  = SH;            // [64][136] = 8704 us
    unsigned short* Kf = SH + 8704;     // [C][24]   = 3072 us max
    unsigned short* Vt = SH + 11776;    // [16][136] = 2176 us
    unsigned short* QT = SH + 13952;    // [16][136] = 2176 us
    unsigned short* Qb = SH + 16128;    // [64][24]  = 1536 us

    for (int i = tid; i < 64 * (C / 8); i += 256) {
        int nn = i & 63, c0 = i >> 6;
        us8 v;
#pragma unroll
        for (int j = 0; j < 8; j++)
            v[j] = f2bs_r(cmap[(size_t)(c0 * 8 + j) * 512 + nq * 64 + nn]);
        *(us8*)&T[nn * 136 + c0 * 8] = v;
    }
    for (int i = tid; i < C * 2; i += 256) {
        int c = i >> 1, hf = i & 1;
        const unsigned short* base = qkv + ((size_t)(bt * C + c)) * 192 + h * 16 + hf * 8;
        us8 qv = *(const us8*)(base);
        us8 kv = *(const us8*)(base + 64);
        us8 vv = *(const us8*)(base + 128);
        *(us8*)&Kf[c * 24 + hf * 8] = kv;
#pragma unroll
        for (int e = 0; e < 8; e++) {
            QT[(hf * 8 + e) * 136 + c] = qv[e];
            Vt[(hf * 8 + e) * 136 + c] = vv[e];
        }
    }
    __syncthreads();

    const f32x4 z4 = {0.f, 0.f, 0.f, 0.f};
    const bf16x8 zb = {0, 0, 0, 0, 0, 0, 0, 0};
    f32x4 qac = z4;
    for (int kk = 0; kk < C; kk += 32) {
        bf16x8 bwq = *(bf16x8*)&QT[l15 * 136 + kk + g * 8];
        bf16x8 af = *(bf16x8*)&T[(w * 16 + l15) * 136 + kk + g * 8];
        qac = __builtin_amdgcn_mfma_f32_16x16x32_bf16(af, bwq, qac, 0, 0, 0);
    }
    const float qs = SCALE_H * LOG2E;
#pragma unroll
    for (int r = 0; r < 4; r++) {
        int row = w * 16 + g * 4 + r;
        Qb[row * 24 + l15] = f2bs_r(qac[r] * qs);
    }
    __syncthreads();   // T reads done; alias as P-bounce

    unsigned short* Pl = SH;   // [64][40] aliases T
    const bf16x8 onesb = {BF16_ONE, BF16_ONE, BF16_ONE, BF16_ONE,
                          BF16_ONE, BF16_ONE, BF16_ONE, BF16_ONE};
    f32x4 O = z4;
    f32x4 R = z4;   // MFMA row-sums

    for (int mc = 0; mc < C; mc += 32) {
        bf16x8 kva = (g < 2) ? *(bf16x8*)&Kf[(mc + l15) * 24 + g * 8] : zb;
        bf16x8 kvb = (g < 2) ? *(bf16x8*)&Kf[(mc + 16 + l15) * 24 + g * 8] : zb;
        bf16x8 vf  = *(bf16x8*)&Vt[l15 * 136 + mc + g * 8];
        bf16x8 qf2 = (g < 2) ? *(bf16x8*)&Qb[(w * 16 + l15) * 24 + g * 8] : zb;
        f32x4 sa = __builtin_amdgcn_mfma_f32_16x16x32_bf16(kva, qf2, z4, 0, 0, 0);
        f32x4 sb = __builtin_amdgcn_mfma_f32_16x16x32_bf16(kvb, qf2, z4, 0, 0, 0);
        us4 wa, wb2;
#pragma unroll
        for (int r = 0; r < 4; r++) {
            wa[r]  = f2bs_r(__builtin_amdgcn_exp2f(sa[r]));
            wb2[r] = f2bs_r(__builtin_amdgcn_exp2f(sb[r]));
        }
        *(us4*)&Pl[(w * 16 + l15) * 40 + g * 4] = wa;
        *(us4*)&Pl[(w * 16 + l15) * 40 + 16 + g * 4] = wb2;

        bf16x8 pf = *(bf16x8*)&Pl[(w * 16 + l15) * 40 + g * 8];
        O = __builtin_amdgcn_mfma_f32_16x16x32_bf16(pf, vf, O, 0, 0, 0);
        R = __builtin_amdgcn_mfma_f32_16x16x32_bf16(pf, onesb, R, 0, 0, 0);
    }

#pragma unroll
    for (int r = 0; r < 4; r++)
        oacc[r] += O[r] / R[r];
    __syncthreads();
}

__global__ __launch_bounds__(256) void attn_all(AttnArgs aa)
{
    __shared__ unsigned short SH[19072];   // 38144 B union -> 4 blocks/CU
    // Per-branch balanced XCD swizzle (hw -> logical).
    const int hw = blockIdx.x;
    int bid;
    if (hw < 768) {
        int m = hw & 7, s = hw >> 3;            // s in [0,96)
        bid = (m * 24 + (s >> 2)) * 4 + (s & 3);
    } else if (hw < 2304) {
        int r = hw - 768;
        int m = r & 7, s = r >> 3;              // s in [0,192)
        bid = 768 + (m * 24 + (s >> 3)) * 8 + (s & 7);
    } else {
        bid = hw;
    }
    const int tid = threadIdx.x;
    const int lane = tid & 63, w = tid >> 6;
    const int l15 = lane & 15, g = lane >> 4;

    if (bid < 768) {
        // ================= spatial differential attention =================
        unsigned short* Kl = SH;            // [512][16] = 8192 us
        unsigned short* Vt = SH + 8192;     // [16][520] = 8320 us
        unsigned short* Pl = SH + 16512;    // [4][16][40] = 2560 us
        const unsigned short* P = aa.P;

        const int bth = bid >> 2, qc = bid & 3;
        const int h = bth & 3, bt = bth >> 2;

        const unsigned short* kbase = P + (size_t)bt * N_ * 512 + 64 + h * 16;
        const unsigned short* vbase = P + (size_t)bt * N_ * 512 + 128 + h * 16;
        const float kscale = SCALE_S * LOG2E;
        for (int i = tid; i < 512; i += 256) {
            us8 k0 = *(const us8*)(kbase + (size_t)i * 512);
            us8 k1 = *(const us8*)(kbase + (size_t)i * 512 + 8);
            us8 s0, s1;
#pragma unroll
            for (int r = 0; r < 8; r++) {
                s0[r] = f2bs_r(b2f(k0[r]) * kscale);
                s1[r] = f2bs_r(b2f(k1[r]) * kscale);
            }
            *(us8*)&Kl[i * 16] = s0;
            *(us8*)&Kl[i * 16 + 8] = s1;
            us8 v0 = *(const us8*)(vbase + (size_t)i * 512);
            us8 v1 = *(const us8*)(vbase + (size_t)i * 512 + 8);
#pragma unroll
            for (int e = 0; e < 8; e++) { Vt[e * 520 + i] = v0[e]; Vt[(8 + e) * 520 + i] = v1[e]; }
        }
        __syncthreads();

        float e1 = 0.f, e2 = 0.f;
#pragma unroll
        for (int j = 0; j < 8; j++) { e1 += aa.lq1[j] * aa.lk1[j]; e2 += aa.lq2[j] * aa.lk2[j]; }
        const float lam = __expf(e1) - __expf(e2) + LAMBDA_INIT;

        const int q0 = qc * 128 + w * 32;

        bf16x8 qf[2];
#pragma unroll
        for (int qt = 0; qt < 2; qt++)
            qf[qt] = *(const bf16x8*)(P + ((size_t)bt * N_ + q0 + qt * 16 + l15) * 512 + h * 16 + (g & 1) * 8);

        const f32x4 z4 = {0.f, 0.f, 0.f, 0.f};
        const bf16x8 zb = {0, 0, 0, 0, 0, 0, 0, 0};
        const bf16x8 onesb = {BF16_ONE, BF16_ONE, BF16_ONE, BF16_ONE,
                              BF16_ONE, BF16_ONE, BF16_ONE, BF16_ONE};
        f32x4 O1[2], O2[2], R1[2], R2[2];
#pragma unroll
        for (int qt = 0; qt < 2; qt++)
#pragma unroll
            for (int r = 0; r < 4; r++) {
                O1[qt][r] = 0.f; O2[qt][r] = 0.f;
                R1[qt][r] = 0.f; R2[qt][r] = 0.f;
            }

        for (int mc = 0; mc < 512; mc += 32) {
            bf16x8 kva = *(bf16x8*)&Kl[(mc + l15) * 16 + (g & 1) * 8];
            bf16x8 kvb = *(bf16x8*)&Kl[(mc + 16 + l15) * 16 + (g & 1) * 8];
            bf16x8 a1a = (g == 0) ? kva : zb, a2a = (g == 1) ? kva : zb;
            bf16x8 a1b = (g == 0) ? kvb : zb, a2b = (g == 1) ? kvb : zb;
            bf16x8 vf = *(bf16x8*)&Vt[l15 * 520 + mc + g * 8];

            f32x4 s1a[2], s1b[2], s2a[2], s2b[2];
#pragma unroll
            for (int qt = 0; qt < 2; qt++) {
                s1a[qt] = __builtin_amdgcn_mfma_f32_16x16x32_bf16(a1a, qf[qt], z4, 0, 0, 0);
                s1b[qt] = __builtin_amdgcn_mfma_f32_16x16x32_bf16(a1b, qf[qt], z4, 0, 0, 0);
                s2a[qt] = __builtin_amdgcn_mfma_f32_16x16x32_bf16(a2a, qf[qt], z4, 0, 0, 0);
                s2b[qt] = __builtin_amdgcn_mfma_f32_16x16x32_bf16(a2b, qf[qt], z4, 0, 0, 0);
            }

            // qt-sequenced through the halved Pl [16 rows/wave]
#pragma unroll
            for (int qt = 0; qt < 2; qt++) {
                us4 w0, w1;
#pragma unroll
                for (int r = 0; r < 4; r++) {
                    w0[r] = f2bs_r(__builtin_amdgcn_exp2f(s1a[qt][r]));
                    w1[r] = f2bs_r(__builtin_amdgcn_exp2f(s1b[qt][r]));
                }
                *(us4*)&Pl[(w * 16 + l15) * 40 + g * 4] = w0;
                *(us4*)&Pl[(w * 16 + l15) * 40 + 16 + g * 4] = w1;
                bf16x8 pf = *(bf16x8*)&Pl[(w * 16 + l15) * 40 + g * 8];
                O1[qt] = __builtin_amdgcn_mfma_f32_16x16x32_bf16(pf, vf, O1[qt], 0, 0, 0);
                R1[qt] = __builtin_amdgcn_mfma_f32_16x16x32_bf16(pf, onesb, R1[qt], 0, 0, 0);

                us4 v0, v1;
#pragma unroll
                for (int r = 0; r < 4; r++) {
                    v0[r] = f2bs_r(__builtin_amdgcn_exp2f(s2a[qt][r]));
                    v1[r] = f2bs_r(__builtin_amdgcn_exp2f(s2b[qt][r]));
                }
                *(us4*)&Pl[(w * 16 + l15) * 40 + g * 4] = v0;
                *(us4*)&Pl[(w * 16 + l15) * 40 + 16 + g * 4] = v1;
                bf16x8 pf2 = *(bf16x8*)&Pl[(w * 16 + l15) * 40 + g * 8];
                O2[qt] = __builtin_amdgcn_mfma_f32_16x16x32_bf16(pf2, vf, O2[qt], 0, 0, 0);
                R2[qt] = __builtin_amdgcn_mfma_f32_16x16x32_bf16(pf2, onesb, R2[qt], 0, 0, 0);
            }
        }

        const float sw = aa.subln[l15];
#pragma unroll
        for (int qt = 0; qt < 2; qt++) {
#pragma unroll
            for (int r = 0; r < 4; r++) {
                int qrow = g * 4 + r;
                float o = O1[qt][r] / R1[qt][r] - lam * (O2[qt][r] / R2[qt][r]);
                float ss = o * o;
                ss += __shfl_xor(ss, 1); ss += __shfl_xor(ss, 2);
                ss += __shfl_xor(ss, 4); ss += __shfl_xor(ss, 8);
                float rms = rsqrtf(ss * (1.0f / 16.0f) + EPS_);
                float val = 0.8f * o * rms * sw;
                int q = q0 + qt * 16 + qrow;
                aa.st[((size_t)bt * N_ + q) * 256 + h * 16 + l15] = f2bs_r(val);
            }
        }
    } else if (bid < 2304) {
        // ======== dtw-aggregated spatial attention (64-row n-chunks) ========
        const int r0 = bid - 768;           // [0,1536)
        const int bth = r0 >> 3, nq = r0 & 7;
        const int h = bth & 3, bt = bth >> 2;

        float oacc[4] = {};
        agg_phase64<64>(aa.qkv0, aa.map0, SH, bt, h, nq, tid, w, l15, g, oacc);
        agg_phase64<128>(aa.qkv1, aa.map1, SH, bt, h, nq, tid, w, l15, g, oacc);

#pragma unroll
        for (int r = 0; r < 4; r++) {
            int n = nq * 64 + w * 16 + g * 4 + r;
            aa.st[((size_t)(bt * N_ + n)) * 256 + 64 + h * 16 + l15] = f2bs_r(oacc[r]);
        }
    } else {
        // ========== temporal + agg-temporal (2 n per 256-thr block) ==========
        const int r0 = bid - 2304;          // [0,1024)
        const int flat = r0 * 2;
        const int b = flat >> 9;
        const int n0 = flat & 511;
        const int p = tid >> 7;             // which n
        const int t127 = tid & 127;
        const int n = n0 + p;
        unsigned short* Pt = SH + p * (T_ * 328);   // [12][328]
        const unsigned short* P = aa.P;

        for (int i = t127; i < T_ * 40; i += 128) {
            int u = i / 40, c8 = i % 40;
            *(us8*)&Pt[u * 328 + c8 * 8] =
                *(const us8*)(P + (((size_t)(b * T_ + u) * N_) + n) * 512 + 192 + c8 * 8);
        }
        __syncthreads();

        if (t127 < 96) {
            const int part = t127 / 48;
            const int rem = t127 % 48;
            const int h = rem / T_, t = rem % T_;

            float q[16];
            if (!part) {
                us8 a0 = *(const us8*)&Pt[t * 328 + h * 16];
                us8 bq = *(const us8*)&Pt[t * 328 + h * 16 + 8];
#pragma unroll
                for (int f = 0; f < 8; f++) { q[f] = b2f(a0[f]); q[8 + f] = b2f(bq[f]); }
            } else {
                float wseg[SEG_];
#pragma unroll
                for (int s = 0; s < SEG_; s++)
                    wseg[s] = aa.ti[(((size_t)b * N_ + n) * T_ + t) * SEG_ + s];
#pragma unroll
                for (int f = 0; f < 16; f++) q[f] = 0.f;
                for (int s = 0; s < SEG_; s++) {
                    const float* qa = aa.tq + ((size_t)n * SEG_ + s) * 64 + h * 16;
#pragma unroll
                    for (int f = 0; f < 16; f++) q[f] += wseg[s] * qa[f];
                }
            }
            const int kc = part ? 192 : 64;
            const int vc = part ? 256 : 128;

            float sc[T_]; float mx = -1e30f;
            for (int u = 0; u < T_; u++) {
                us8 a0 = *(const us8*)&Pt[u * 328 + kc + h * 16];
                us8 bk = *(const us8*)&Pt[u * 328 + kc + h * 16 + 8];
                float s = 0.f;
#pragma unroll
                for (int f = 0; f < 8; f++) s += q[f] * b2f(a0[f]) + q[8 + f] * b2f(bk[f]);
                s *= SCALE_H;
                sc[u] = s; mx = fmaxf(mx, s);
            }
            float sum = 0.f;
            for (int u = 0; u < T_; u++) { sc[u] = __expf(sc[u] - mx); sum += sc[u]; }
            float inv = 1.0f / sum;
            float o[16] = {};
            for (int u = 0; u < T_; u++) {
                us8 a0 = *(const us8*)&Pt[u * 328 + vc + h * 16];
                us8 bv = *(const us8*)&Pt[u * 328 + vc + h * 16 + 8];
                float ww = sc[u] * inv;
#pragma unroll
                for (int f = 0; f < 8; f++) { o[f] += ww * b2f(a0[f]); o[8 + f] += ww * b2f(bv[f]); }
            }
            unsigned short* orow = aa.st + (((size_t)(b * T_ + t) * N_) + n) * 256 + (part ? 192 : 128) + h * 16;
            us8 w0, w1;
#pragma unroll
            for (int f = 0; f < 8; f++) { w0[f] = f2bs_r(o[f]); w1[f] = f2bs_r(o[8 + f]); }
            *(us8*)orow = w0;
            *(us8*)(orow + 8) = w1;
        }
    }
}

// ===========================================================================
// Output projection (128x128 tile), fp32 out, bias = folded b_agg.
// ===========================================================================
__global__ __launch_bounds__(256) void out_proj(
    const unsigned short* __restrict__ A, const unsigned short* __restrict__ W,
    const float* __restrict__ bias, float* __restrict__ O)
{
    __shared__ unsigned short As[128 * 64];
    __shared__ unsigned short Ws[128 * 64];
    const int m0 = blockIdx.x * 128;
    const int e0 = blockIdx.y * 128;
    const int tid = threadIdx.x;
    const int lane = tid & 63;
    const int wid = tid >> 6;
    const int wm = wid >> 1, wn = wid & 1;
    const int l15 = lane & 15, l4 = lane >> 4;
    const int K = 256;

    f32x4 acc[4][4];
#pragma unroll
    for (int i = 0; i < 4; i++)
#pragma unroll
        for (int j = 0; j < 4; j++)
#pragma unroll
            for (int r = 0; r < 4; r++) acc[i][j][r] = 0.f;

    for (int kk = 0; kk < K; kk += 64) {
#pragma unroll
        for (int p = 0; p < 4; p++) {
            int off = p * 2048 + tid * 8;
            int r = off >> 6, cc = off & 63;
            GLOAD16(&A[(size_t)(m0 + r) * K + kk + cc], &As[p * 2048 + wid * 512]);
        }
#pragma unroll
        for (int p = 0; p < 4; p++) {
            int off = p * 2048 + tid * 8;
            int r = off >> 6, cc = off & 63;
            GLOAD16(&W[(size_t)(e0 + r) * K + kk + cc], &Ws[p * 2048 + wid * 512]);
        }
        __syncthreads();
#pragma unroll
        for (int ks = 0; ks < 64; ks += 32) {
            bf16x8 af[4], bw[4];
#pragma unroll
            for (int i = 0; i < 4; i++)
                af[i] = *(bf16x8*)(&As[(wm * 64 + i * 16 + l15) * 64 + ks + l4 * 8]);
#pragma unroll
            for (int j = 0; j < 4; j++)
                bw[j] = *(bf16x8*)(&Ws[(wn * 64 + j * 16 + l15) * 64 + ks + l4 * 8]);
#pragma unroll
            for (int i = 0; i < 4; i++)
#pragma unroll
                for (int j = 0; j < 4; j++)
                    acc[i][j] = __builtin_amdgcn_mfma_f32_16x16x32_bf16(af[i], bw[j], acc[i][j], 0, 0, 0);
        }
        __syncthreads();
    }

#pragma unroll
    for (int i = 0; i < 4; i++)
#pragma unroll
        for (int j = 0; j < 4; j++) {
            int row0 = m0 + wm * 64 + i * 16 + l4 * 4;
            int col = e0 + wn * 64 + j * 16 + l15;
            float bv = bias[col];
#pragma unroll
            for (int r = 0; r < 4; r++)
                O[(size_t)(row0 + r) * 256 + col] = acc[i][j][r] + bv;
        }
}

// ===========================================================================
extern "C" void kernel_launch(void* const* d_in, const int* in_sizes, int n_in,
                              void* d_out, int out_size, void* d_ws, size_t ws_size,
                              hipStream_t stream)
{
    const float* x      = (const float*)d_in[0];
    const float* dtw0   = (const float*)d_in[1];
    const float* dtw1   = (const float*)d_in[2];
    const float* map0   = (const float*)d_in[3];
    const float* map1   = (const float*)d_in[4];
    const float* tmpinf = (const float*)d_in[5];
    const float* lq1    = (const float*)d_in[9];
    const float* lk1    = (const float*)d_in[10];
    const float* lq2    = (const float*)d_in[11];
    const float* lk2    = (const float*)d_in[12];
    const float* subln  = (const float*)d_in[13];
    const float* Wagg_f = (const float*)d_in[20];
    const float* b_agg  = (const float*)d_in[21];
    const float* tq     = (const float*)d_in[25];
    const float* Wout_f = (const float*)d_in[28];
    float* out = (float*)d_out;

    const size_t M = (size_t)BT_ * N_;   // 24576

    char* w = (char*)d_ws;
    unsigned short* P     = (unsigned short*)w;   w += M * 512 * 2;
    unsigned short* st    = (unsigned short*)w;   w += M * 256 * 2;
    unsigned short* qkv0b = (unsigned short*)w;   w += (size_t)BT_ * 64 * 192 * 2;
    unsigned short* qkv1b = (unsigned short*)w;   w += (size_t)BT_ * 128 * 192 * 2;
    unsigned short* xb    = (unsigned short*)w;   w += M * 256 * 2;
    unsigned short* d0b   = (unsigned short*)w;   w += (size_t)BT_ * 64 * 256 * 2;
    unsigned short* d1b   = (unsigned short*)w;   w += (size_t)BT_ * 128 * 256 * 2;
    unsigned short* wb    = (unsigned short*)w;   w += 299008 * 2;
    float*          bvec  = (float*)w;            w += 256 * 4;

    unsigned short* Wproj = wb;
    unsigned short* Wd0   = wb + 131072;
    unsigned short* Wd1   = wb + 180224;
    unsigned short* Weff  = wb + 233472;

    dim3 blk(256);

    // 1. conversions + Wagg fold (disjoint writes within one launch)
    ConvArgs ca;
    ca.x = x; ca.d0 = dtw0; ca.d1 = dtw1;
    ca.wp[0] = (const float*)d_in[6];  ca.wp[1] = (const float*)d_in[7];  ca.wp[2] = (const float*)d_in[8];
    ca.wp[3] = (const float*)d_in[22]; ca.wp[4] = (const float*)d_in[23]; ca.wp[5] = (const float*)d_in[24];
    ca.wp[6] = (const float*)d_in[26]; ca.wp[7] = (const float*)d_in[27];
    ca.wp[8] = (const float*)d_in[14]; ca.wp[9] = (const float*)d_in[15]; ca.wp[10] = (const float*)d_in[16];
    ca.wp[11] = (const float*)d_in[17]; ca.wp[12] = (const float*)d_in[18]; ca.wp[13] = (const float*)d_in[19];
    ca.wp[14] = Wagg_f; ca.wp[15] = Wout_f;
    ca.bagg = b_agg;
    ca.xb = xb; ca.d0b = d0b; ca.d1b = d1b; ca.wb = wb; ca.bvec = bvec;
    hipLaunchKernelGGL(prep_all, dim3(NCONVBLK + 16), blk, 0, stream, ca);

    // 2. all projections (P + dtw) in one launch
    ProjArgs pa;
    pa.xb = xb; pa.Wproj = Wproj;
    pa.d0b = d0b; pa.d1b = d1b; pa.Wd0 = Wd0; pa.Wd1 = Wd1;
    pa.P = P; pa.q0b = qkv0b; pa.q1b = qkv1b;
    hipLaunchKernelGGL(proj_all, dim3(984), blk, 0, stream, pa);

    // 3. all attention branches in one launch (balanced XCD swizzle)
    AttnArgs aa;
    aa.P = P; aa.qkv0 = qkv0b; aa.qkv1 = qkv1b;
    aa.map0 = map0; aa.map1 = map1;
    aa.lq1 = lq1; aa.lk1 = lk1; aa.lq2 = lq2; aa.lk2 = lk2; aa.subln = subln;
    aa.tq = tq; aa.ti = tmpinf; aa.st = st;
    hipLaunchKernelGGL(attn_all, dim3(3328), blk, 0, stream, aa);

    // 4. output projection
    hipLaunchKernelGGL(out_proj, dim3(192, 2), blk, 0, stream,
                       st, Weff, bvec, out);
}

// Round 19
// 88.334 us; speedup vs baseline: 1.0212x; 1.0189x over previous
//
#include <hip/hip_runtime.h>
#include <hip/hip_bf16.h>
#include <cstddef>

#define B_ 4
#define T_ 12
#define N_ 512
#define D_ 256
#define H_ 4
#define SEG_ 6
#define BT_ (B_*T_)

#define SCALE_S 0.35355339059327373f   /* 8^-0.5  */
#define SCALE_H 0.25f                  /* 16^-0.5 */
#define LOG2E   1.44269504088896340736f
#define LAMBDA_INIT 0.2f
#define EPS_ 1e-6f

typedef short bf16x8 __attribute__((ext_vector_type(8)));
typedef float f32x4 __attribute__((ext_vector_type(4)));
typedef unsigned short us8 __attribute__((ext_vector_type(8)));
typedef unsigned short us4 __attribute__((ext_vector_type(4)));

__device__ inline float b2f(unsigned short u) {
    union { unsigned int i; float f; } x; x.i = ((unsigned int)u) << 16; return x.f;
}
// library convert (RNE + NaN handling) — prep only
__device__ inline unsigned short f2bs(float f) {
    __hip_bfloat16 b = __float2bfloat16(f);
    return *(unsigned short*)&b;
}
// fast 2-op bf16 pack (round-half-up; finite values) — hot loops
__device__ inline unsigned short f2bs_r(float f) {
    union { float f; unsigned int u; } x; x.f = f;
    return (unsigned short)((x.u + 0x8000u) >> 16);
}

#define GLOAD16(gsrc, ldst) \
    __builtin_amdgcn_global_load_lds((const __attribute__((address_space(1))) void*)(gsrc), \
                                     (__attribute__((address_space(3))) void*)(ldst), 16, 0, 0)

// ===========================================================================
// prep_all: blocks [0,4370) = fp32->bf16 conversions;
//           blocks [4370,4386) = Wagg fold into Weff cols [64,128) + bvec.
// Conv branch SKIPS Weff cols [64,128) — fold blocks are the sole writers.
// ===========================================================================
struct ConvArgs {
    const float* x; const float* d0; const float* d1;
    const float* wp[16];
    const float* bagg;
    unsigned short* xb; unsigned short* d0b; unsigned short* d1b; unsigned short* wb;
    float* bvec;
};
#define CSEG0 6291456
#define CSEG1 (CSEG0 + 786432)
#define CSEG2 (CSEG1 + 1572864)
#define CTOT  (CSEG2 + 299008)
#define NCONVBLK 4370   /* CTOT/8/256 */

__global__ __launch_bounds__(256) void prep_all(ConvArgs a)
{
    __shared__ float waggl[64 * 64];
    __shared__ float woutl[16 * 64];

    if (blockIdx.x >= NCONVBLK) {
        const float* wout = a.wp[15];
        const float* wagg = a.wp[14];
        unsigned short* weff = a.wb + 233472;
        const int tid = threadIdx.x;
        const int e0 = (blockIdx.x - NCONVBLK) * 16;
        for (int i = tid; i < 4096; i += 256) waggl[i] = wagg[i];
        for (int i = tid; i < 16 * 64; i += 256) {
            int er = i >> 6, j = i & 63;
            woutl[i] = wout[(size_t)(e0 + er) * 256 + 64 + j];
        }
        __syncthreads();
        for (int o = tid; o < 1024; o += 256) {
            int er = o >> 6, c = o & 63;
            float acc = 0.f;
#pragma unroll
            for (int j = 0; j < 64; j++) acc += woutl[er * 64 + j] * waggl[j * 64 + c];
            weff[(size_t)(e0 + er) * 256 + 64 + c] = f2bs(acc);
        }
        if (tid < 16) {
            float acc = 0.f;
            for (int j = 0; j < 64; j++) acc += a.bagg[j] * woutl[tid * 64 + j];
            a.bvec[e0 + tid] = acc;
        }
        return;
    }

    long long i = (long long)(blockIdx.x * 256 + threadIdx.x) * 8;
    const float* src; unsigned short* dst; long long rel;
    if (i < CSEG0)      { src = a.x;  dst = a.xb;  rel = i; }
    else if (i < CSEG1) { src = a.d0; dst = a.d0b; rel = i - CSEG0; }
    else if (i < CSEG2) { src = a.d1; dst = a.d1b; rel = i - CSEG1; }
    else {
        int widx = (int)(i - CSEG2);
#pragma unroll
        for (int k = 0; k < 8; k++) {
            int idx = widx + k;
            if (idx >= 233472) {
                int c = (idx - 233472) & 255;
                if (c >= 64 && c < 128) continue;   // fold blocks own these
            }
            const float* s; int r;
            if (idx < 131072)      { s = a.wp[idx >> 14]; r = idx & 16383; }
            else if (idx < 180224) { int q = idx - 131072; s = a.wp[8 + (q >> 14)]; r = q & 16383; }
            else if (idx < 229376) { int q = idx - 180224; s = a.wp[11 + (q >> 14)]; r = q & 16383; }
            else if (idx < 233472) { s = a.wp[14]; r = idx - 229376; }
            else                   { s = a.wp[15]; r = idx - 233472; }
            a.wb[idx] = f2bs(s[r]);
        }
        return;
    }
    float4 v0 = *(const float4*)(src + rel);
    float4 v1 = *(const float4*)(src + rel + 4);
    us8 o;
    o[0] = f2bs(v0.x); o[1] = f2bs(v0.y); o[2] = f2bs(v0.z); o[3] = f2bs(v0.w);
    o[4] = f2bs(v1.x); o[5] = f2bs(v1.y); o[6] = f2bs(v1.z); o[7] = f2bs(v1.w);
    *(us8*)(dst + rel) = o;
}

// ===========================================================================
// proj_all: blocks [0,768) = P-projection GEMM (128x128 tile);
//           blocks [768,984) = both dtw projections (128x64 tile).
// ===========================================================================
struct ProjArgs {
    const unsigned short *xb, *Wproj;
    const unsigned short *d0b, *d1b, *Wd0, *Wd1;
    unsigned short *P, *q0b, *q1b;
};

__global__ __launch_bounds__(256) void proj_all(ProjArgs pa)
{
    __shared__ unsigned short As[128 * 64];
    __shared__ unsigned short Ws[128 * 64];
    const int tid = threadIdx.x;
    const int lane = tid & 63;
    const int wid = tid >> 6;
    const int wm = wid >> 1, wn = wid & 1;
    const int l15 = lane & 15, l4 = lane >> 4;
    const int bid = blockIdx.x;

    if (bid < 768) {
        const int m0 = (bid % 192) * 128;
        const int e0 = (bid / 192) * 128;
        const unsigned short* A = pa.xb;
        const unsigned short* W = pa.Wproj;
        const int K = 256;

        f32x4 acc[4][4];
#pragma unroll
        for (int i = 0; i < 4; i++)
#pragma unroll
            for (int j = 0; j < 4; j++)
#pragma unroll
                for (int r = 0; r < 4; r++) acc[i][j][r] = 0.f;

        for (int kk = 0; kk < K; kk += 64) {
#pragma unroll
            for (int p = 0; p < 4; p++) {
                int off = p * 2048 + tid * 8;
                int r = off >> 6, cc = off & 63;
                GLOAD16(&A[(size_t)(m0 + r) * K + kk + cc], &As[p * 2048 + wid * 512]);
            }
#pragma unroll
            for (int p = 0; p < 4; p++) {
                int off = p * 2048 + tid * 8;
                int r = off >> 6, cc = off & 63;
                GLOAD16(&W[(size_t)(e0 + r) * K + kk + cc], &Ws[p * 2048 + wid * 512]);
            }
            __syncthreads();
#pragma unroll
            for (int ks = 0; ks < 64; ks += 32) {
                bf16x8 af[4], bw[4];
#pragma unroll
                for (int i = 0; i < 4; i++)
                    af[i] = *(bf16x8*)(&As[(wm * 64 + i * 16 + l15) * 64 + ks + l4 * 8]);
#pragma unroll
                for (int j = 0; j < 4; j++)
                    bw[j] = *(bf16x8*)(&Ws[(wn * 64 + j * 16 + l15) * 64 + ks + l4 * 8]);
#pragma unroll
                for (int i = 0; i < 4; i++)
#pragma unroll
                    for (int j = 0; j < 4; j++)
                        acc[i][j] = __builtin_amdgcn_mfma_f32_16x16x32_bf16(af[i], bw[j], acc[i][j], 0, 0, 0);
            }
            __syncthreads();
        }
#pragma unroll
        for (int i = 0; i < 4; i++)
#pragma unroll
            for (int j = 0; j < 4; j++) {
                int row0 = m0 + wm * 64 + i * 16 + l4 * 4;
                int col = e0 + wn * 64 + j * 16 + l15;
#pragma unroll
                for (int r = 0; r < 4; r++)
                    pa.P[(size_t)(row0 + r) * 512 + col] = f2bs(acc[i][j][r]);
            }
    } else {
        const int r0 = bid - 768;
        const int bx = r0 % 72, by = r0 / 72;
        const unsigned short *A, *W; unsigned short* O;
        int m0;
        if (bx < 24) { A = pa.d0b; W = pa.Wd0; O = pa.q0b; m0 = bx * 128; }
        else         { A = pa.d1b; W = pa.Wd1; O = pa.q1b; m0 = (bx - 24) * 128; }
        const int K = 256, ldo = 192;
        const int e0 = by * 64;

        f32x4 acc[4][2];
#pragma unroll
        for (int i = 0; i < 4; i++)
#pragma unroll
            for (int j = 0; j < 2; j++)
#pragma unroll
                for (int r = 0; r < 4; r++) acc[i][j][r] = 0.f;

        for (int kk = 0; kk < K; kk += 64) {
#pragma unroll
            for (int p = 0; p < 4; p++) {
                int off = p * 2048 + tid * 8;
                int r = off >> 6, cc = off & 63;
                GLOAD16(&A[(size_t)(m0 + r) * K + kk + cc], &As[p * 2048 + wid * 512]);
            }
#pragma unroll
            for (int p = 0; p < 2; p++) {
                int off = p * 2048 + tid * 8;
                int r = off >> 6, cc = off & 63;
                GLOAD16(&W[(size_t)(e0 + r) * K + kk + cc], &Ws[p * 2048 + wid * 512]);
            }
            __syncthreads();
#pragma unroll
            for (int ks = 0; ks < 64; ks += 32) {
                bf16x8 af[4], bw[2];
#pragma unroll
                for (int i = 0; i < 4; i++)
                    af[i] = *(bf16x8*)(&As[(wm * 64 + i * 16 + l15) * 64 + ks + l4 * 8]);
#pragma unroll
                for (int j = 0; j < 2; j++)
                    bw[j] = *(bf16x8*)(&Ws[(wn * 32 + j * 16 + l15) * 64 + ks + l4 * 8]);
#pragma unroll
                for (int i = 0; i < 4; i++)
#pragma unroll
                    for (int j = 0; j < 2; j++)
                        acc[i][j] = __builtin_amdgcn_mfma_f32_16x16x32_bf16(af[i], bw[j], acc[i][j], 0, 0, 0);
            }
            __syncthreads();
        }
#pragma unroll
        for (int i = 0; i < 4; i++)
#pragma unroll
            for (int j = 0; j < 2; j++) {
                int row0 = m0 + wm * 64 + i * 16 + l4 * 4;
                int col = e0 + wn * 32 + j * 16 + l15;
#pragma unroll
                for (int r = 0; r < 4; r++)
                    O[(size_t)(row0 + r) * ldo + col] = f2bs(acc[i][j][r]);
            }
    }
}

// ===========================================================================
// attn_all — r15 config (balanced XCD swizzle, LDS 51456 B, no setprio).
// ===========================================================================
struct AttnArgs {
    const unsigned short* P;
    const unsigned short *qkv0, *qkv1;
    const float *map0, *map1;
    const float *lq1, *lk1, *lq2, *lk2, *subln;
    const float *tq, *ti;
    unsigned short* st;
};

#define BF16_ONE ((short)0x3F80)

template<int C>
__device__ inline void agg_phase64(
    const unsigned short* __restrict__ qkv, const float* __restrict__ cmap,
    unsigned short* SH, int bt, int h, int nq,
    int tid, int w, int l15, int g, float oacc[4])
{
    unsigned short* T  = SH;            // [64][136]
    unsigned short* Kf = SH + 8704;     // [C][40]
    unsigned short* Vt = SH + 13824;    // [16][136]
    unsigned short* QT = SH + 16000;    // [16][136]
    unsigned short* Qb = SH + 18176;    // [64][40]

    for (int i = tid; i < 64 * (C / 8); i += 256) {
        int nn = i & 63, c0 = i >> 6;
        us8 v;
#pragma unroll
        for (int j = 0; j < 8; j++)
            v[j] = f2bs_r(cmap[(size_t)(c0 * 8 + j) * 512 + nq * 64 + nn]);
        *(us8*)&T[nn * 136 + c0 * 8] = v;
    }
    const us8 z8 = {0, 0, 0, 0, 0, 0, 0, 0};
    for (int i = tid; i < C * 2; i += 256) {
        int c = i >> 1, hf = i & 1;
        const unsigned short* base = qkv + ((size_t)(bt * C + c)) * 192 + h * 16 + hf * 8;
        us8 qv = *(const us8*)(base);
        us8 kv = *(const us8*)(base + 64);
        us8 vv = *(const us8*)(base + 128);
        *(us8*)&Kf[c * 40 + hf * 8] = kv;
        *(us8*)&Kf[c * 40 + 16 + hf * 8] = z8;
#pragma unroll
        for (int e = 0; e < 8; e++) {
            QT[(hf * 8 + e) * 136 + c] = qv[e];
            Vt[(hf * 8 + e) * 136 + c] = vv[e];
        }
    }
    __syncthreads();

    const f32x4 z4 = {0.f, 0.f, 0.f, 0.f};
    f32x4 qac = z4;
    for (int kk = 0; kk < C; kk += 32) {
        bf16x8 bwq = *(bf16x8*)&QT[l15 * 136 + kk + g * 8];
        bf16x8 af = *(bf16x8*)&T[(w * 16 + l15) * 136 + kk + g * 8];
        qac = __builtin_amdgcn_mfma_f32_16x16x32_bf16(af, bwq, qac, 0, 0, 0);
    }
    const float qs = SCALE_H * LOG2E;
#pragma unroll
    for (int r = 0; r < 4; r++) {
        int row = w * 16 + g * 4 + r;
        Qb[row * 40 + l15] = f2bs_r(qac[r] * qs);
        Qb[row * 40 + 16 + l15] = 0;
    }
    __syncthreads();   // T reads done; alias as P-bounce

    unsigned short* Pl = SH;   // [64][40] aliases T
    const bf16x8 onesb = {BF16_ONE, BF16_ONE, BF16_ONE, BF16_ONE,
                          BF16_ONE, BF16_ONE, BF16_ONE, BF16_ONE};
    f32x4 O = z4;
    f32x4 R = z4;   // MFMA row-sums

    for (int mc = 0; mc < C; mc += 32) {
        bf16x8 kva = *(bf16x8*)&Kf[(mc + l15) * 40 + g * 8];
        bf16x8 kvb = *(bf16x8*)&Kf[(mc + 16 + l15) * 40 + g * 8];
        bf16x8 vf  = *(bf16x8*)&Vt[l15 * 136 + mc + g * 8];
        bf16x8 qf2 = *(bf16x8*)&Qb[(w * 16 + l15) * 40 + g * 8];
        f32x4 sa = __builtin_amdgcn_mfma_f32_16x16x32_bf16(kva, qf2, z4, 0, 0, 0);
        f32x4 sb = __builtin_amdgcn_mfma_f32_16x16x32_bf16(kvb, qf2, z4, 0, 0, 0);
        us4 wa, wb2;
#pragma unroll
        for (int r = 0; r < 4; r++) {
            wa[r]  = f2bs_r(__builtin_amdgcn_exp2f(sa[r]));
            wb2[r] = f2bs_r(__builtin_amdgcn_exp2f(sb[r]));
        }
        *(us4*)&Pl[(w * 16 + l15) * 40 + g * 4] = wa;
        *(us4*)&Pl[(w * 16 + l15) * 40 + 16 + g * 4] = wb2;

        bf16x8 pf = *(bf16x8*)&Pl[(w * 16 + l15) * 40 + g * 8];
        O = __builtin_amdgcn_mfma_f32_16x16x32_bf16(pf, vf, O, 0, 0, 0);
        R = __builtin_amdgcn_mfma_f32_16x16x32_bf16(pf, onesb, R, 0, 0, 0);
    }

#pragma unroll
    for (int r = 0; r < 4; r++)
        oacc[r] += O[r] / R[r];
    __syncthreads();
}

__global__ __launch_bounds__(256) void attn_all(AttnArgs aa)
{
    __shared__ unsigned short SH[25728];   // 51456 B union
    // Per-branch balanced XCD swizzle (hw -> logical).
    const int hw = blockIdx.x;
    int bid;
    if (hw < 768) {
        int m = hw & 7, s = hw >> 3;            // s in [0,96)
        bid = (m * 24 + (s >> 2)) * 4 + (s & 3);
    } else if (hw < 2304) {
        int r = hw - 768;
        int m = r & 7, s = r >> 3;              // s in [0,192)
        bid = 768 + (m * 24 + (s >> 3)) * 8 + (s & 7);
    } else {
        bid = hw;
    }
    const int tid = threadIdx.x;
    const int lane = tid & 63, w = tid >> 6;
    const int l15 = lane & 15, g = lane >> 4;

    if (bid < 768) {
        // ================= spatial differential attention =================
        unsigned short* Kl = SH;            // [512][24] = 12288 us
        unsigned short* Vt = SH + 12288;    // [16][520] =  8320 us
        unsigned short* Pl = SH + 20608;    // [4][32][40] = 5120 us
        const unsigned short* P = aa.P;

        const int bth = bid >> 2, qc = bid & 3;
        const int h = bth & 3, bt = bth >> 2;

        const unsigned short* kbase = P + (size_t)bt * N_ * 512 + 64 + h * 16;
        const unsigned short* vbase = P + (size_t)bt * N_ * 512 + 128 + h * 16;
        const float kscale = SCALE_S * LOG2E;
        for (int i = tid; i < 512; i += 256) {
            us8 k0 = *(const us8*)(kbase + (size_t)i * 512);
            us8 k1 = *(const us8*)(kbase + (size_t)i * 512 + 8);
            us8 s0, s1;
#pragma unroll
            for (int r = 0; r < 8; r++) {
                s0[r] = f2bs_r(b2f(k0[r]) * kscale);
                s1[r] = f2bs_r(b2f(k1[r]) * kscale);
            }
            *(us8*)&Kl[i * 24] = s0;
            *(us8*)&Kl[i * 24 + 8] = s1;
            us8 v0 = *(const us8*)(vbase + (size_t)i * 512);
            us8 v1 = *(const us8*)(vbase + (size_t)i * 512 + 8);
#pragma unroll
            for (int e = 0; e < 8; e++) { Vt[e * 520 + i] = v0[e]; Vt[(8 + e) * 520 + i] = v1[e]; }
        }
        __syncthreads();

        float e1 = 0.f, e2 = 0.f;
#pragma unroll
        for (int j = 0; j < 8; j++) { e1 += aa.lq1[j] * aa.lk1[j]; e2 += aa.lq2[j] * aa.lk2[j]; }
        const float lam = __expf(e1) - __expf(e2) + LAMBDA_INIT;

        const int q0 = qc * 128 + w * 32;

        bf16x8 qf[2];
#pragma unroll
        for (int qt = 0; qt < 2; qt++)
            qf[qt] = *(const bf16x8*)(P + ((size_t)bt * N_ + q0 + qt * 16 + l15) * 512 + h * 16 + (g & 1) * 8);

        const f32x4 z4 = {0.f, 0.f, 0.f, 0.f};
        const bf16x8 zb = {0, 0, 0, 0, 0, 0, 0, 0};
        const bf16x8 onesb = {BF16_ONE, BF16_ONE, BF16_ONE, BF16_ONE,
                              BF16_ONE, BF16_ONE, BF16_ONE, BF16_ONE};
        f32x4 O1[2], O2[2], R1[2], R2[2];
#pragma unroll
        for (int qt = 0; qt < 2; qt++)
#pragma unroll
            for (int r = 0; r < 4; r++) {
                O1[qt][r] = 0.f; O2[qt][r] = 0.f;
                R1[qt][r] = 0.f; R2[qt][r] = 0.f;
            }

        for (int mc = 0; mc < 512; mc += 32) {
            bf16x8 kva = *(bf16x8*)&Kl[(mc + l15) * 24 + (g & 1) * 8];
            bf16x8 kvb = *(bf16x8*)&Kl[(mc + 16 + l15) * 24 + (g & 1) * 8];
            bf16x8 a1a = (g == 0) ? kva : zb, a2a = (g == 1) ? kva : zb;
            bf16x8 a1b = (g == 0) ? kvb : zb, a2b = (g == 1) ? kvb : zb;
            bf16x8 vf = *(bf16x8*)&Vt[l15 * 520 + mc + g * 8];

            f32x4 s1a[2], s1b[2], s2a[2], s2b[2];
#pragma unroll
            for (int qt = 0; qt < 2; qt++) {
                s1a[qt] = __builtin_amdgcn_mfma_f32_16x16x32_bf16(a1a, qf[qt], z4, 0, 0, 0);
                s1b[qt] = __builtin_amdgcn_mfma_f32_16x16x32_bf16(a1b, qf[qt], z4, 0, 0, 0);
                s2a[qt] = __builtin_amdgcn_mfma_f32_16x16x32_bf16(a2a, qf[qt], z4, 0, 0, 0);
                s2b[qt] = __builtin_amdgcn_mfma_f32_16x16x32_bf16(a2b, qf[qt], z4, 0, 0, 0);
            }

#pragma unroll
            for (int qt = 0; qt < 2; qt++) {
                us4 w0, w1;
#pragma unroll
                for (int r = 0; r < 4; r++) {
                    w0[r] = f2bs_r(__builtin_amdgcn_exp2f(s1a[qt][r]));
                    w1[r] = f2bs_r(__builtin_amdgcn_exp2f(s1b[qt][r]));
                }
                *(us4*)&Pl[(w * 32 + qt * 16 + l15) * 40 + g * 4] = w0;
                *(us4*)&Pl[(w * 32 + qt * 16 + l15) * 40 + 16 + g * 4] = w1;
            }
#pragma unroll
            for (int qt = 0; qt < 2; qt++) {
                bf16x8 pf = *(bf16x8*)&Pl[(w * 32 + qt * 16 + l15) * 40 + g * 8];
                O1[qt] = __builtin_amdgcn_mfma_f32_16x16x32_bf16(pf, vf, O1[qt], 0, 0, 0);
                R1[qt] = __builtin_amdgcn_mfma_f32_16x16x32_bf16(pf, onesb, R1[qt], 0, 0, 0);
            }
#pragma unroll
            for (int qt = 0; qt < 2; qt++) {
                us4 w0, w1;
#pragma unroll
                for (int r = 0; r < 4; r++) {
                    w0[r] = f2bs_r(__builtin_amdgcn_exp2f(s2a[qt][r]));
                    w1[r] = f2bs_r(__builtin_amdgcn_exp2f(s2b[qt][r]));
                }
                *(us4*)&Pl[(w * 32 + qt * 16 + l15) * 40 + g * 4] = w0;
                *(us4*)&Pl[(w * 32 + qt * 16 + l15) * 40 + 16 + g * 4] = w1;
            }
#pragma unroll
            for (int qt = 0; qt < 2; qt++) {
                bf16x8 pf = *(bf16x8*)&Pl[(w * 32 + qt * 16 + l15) * 40 + g * 8];
                O2[qt] = __builtin_amdgcn_mfma_f32_16x16x32_bf16(pf, vf, O2[qt], 0, 0, 0);
                R2[qt] = __builtin_amdgcn_mfma_f32_16x16x32_bf16(pf, onesb, R2[qt], 0, 0, 0);
            }
        }

        const float sw = aa.subln[l15];
#pragma unroll
        for (int qt = 0; qt < 2; qt++) {
#pragma unroll
            for (int r = 0; r < 4; r++) {
                int qrow = g * 4 + r;
                float o = O1[qt][r] / R1[qt][r] - lam * (O2[qt][r] / R2[qt][r]);
                float ss = o * o;
                ss += __shfl_xor(ss, 1); ss += __shfl_xor(ss, 2);
                ss += __shfl_xor(ss, 4); ss += __shfl_xor(ss, 8);
                float rms = rsqrtf(ss * (1.0f / 16.0f) + EPS_);
                float val = 0.8f * o * rms * sw;
                int q = q0 + qt * 16 + qrow;
                aa.st[((size_t)bt * N_ + q) * 256 + h * 16 + l15] = f2bs_r(val);
            }
        }
    } else if (bid < 2304) {
        // ======== dtw-aggregated spatial attention (64-row n-chunks) ========
        const int r0 = bid - 768;           // [0,1536)
        const int bth = r0 >> 3, nq = r0 & 7;
        const int h = bth & 3, bt = bth >> 2;

        float oacc[4] = {};
        agg_phase64<64>(aa.qkv0, aa.map0, SH, bt, h, nq, tid, w, l15, g, oacc);
        agg_phase64<128>(aa.qkv1, aa.map1, SH, bt, h, nq, tid, w, l15, g, oacc);

#pragma unroll
        for (int r = 0; r < 4; r++) {
            int n = nq * 64 + w * 16 + g * 4 + r;
            aa.st[((size_t)(bt * N_ + n)) * 256 + 64 + h * 16 + l15] = f2bs_r(oacc[r]);
        }
    } else {
        // ========== temporal + agg-temporal (2 n per 256-thr block) ==========
        const int r0 = bid - 2304;          // [0,1024)
        const int flat = r0 * 2;
        const int b = flat >> 9;
        const int n0 = flat & 511;
        const int p = tid >> 7;             // which n
        const int t127 = tid & 127;
        const int n = n0 + p;
        unsigned short* Pt = SH + p * (T_ * 328);   // [12][328]
        const unsigned short* P = aa.P;

        for (int i = t127; i < T_ * 40; i += 128) {
            int u = i / 40, c8 = i % 40;
            *(us8*)&Pt[u * 328 + c8 * 8] =
                *(const us8*)(P + (((size_t)(b * T_ + u) * N_) + n) * 512 + 192 + c8 * 8);
        }
        __syncthreads();

        if (t127 < 96) {
            const int part = t127 / 48;
            const int rem = t127 % 48;
            const int h = rem / T_, t = rem % T_;

            float q[16];
            if (!part) {
                us8 a0 = *(const us8*)&Pt[t * 328 + h * 16];
                us8 bq = *(const us8*)&Pt[t * 328 + h * 16 + 8];
#pragma unroll
                for (int f = 0; f < 8; f++) { q[f] = b2f(a0[f]); q[8 + f] = b2f(bq[f]); }
            } else {
                float wseg[SEG_];
#pragma unroll
                for (int s = 0; s < SEG_; s++)
                    wseg[s] = aa.ti[(((size_t)b * N_ + n) * T_ + t) * SEG_ + s];
#pragma unroll
                for (int f = 0; f < 16; f++) q[f] = 0.f;
                for (int s = 0; s < SEG_; s++) {
                    const float* qa = aa.tq + ((size_t)n * SEG_ + s) * 64 + h * 16;
#pragma unroll
                    for (int f = 0; f < 16; f++) q[f] += wseg[s] * qa[f];
                }
            }
            const int kc = part ? 192 : 64;
            const int vc = part ? 256 : 128;

            float sc[T_]; float mx = -1e30f;
            for (int u = 0; u < T_; u++) {
                us8 a0 = *(const us8*)&Pt[u * 328 + kc + h * 16];
                us8 bk = *(const us8*)&Pt[u * 328 + kc + h * 16 + 8];
                float s = 0.f;
#pragma unroll
                for (int f = 0; f < 8; f++) s += q[f] * b2f(a0[f]) + q[8 + f] * b2f(bk[f]);
                s *= SCALE_H;
                sc[u] = s; mx = fmaxf(mx, s);
            }
            float sum = 0.f;
            for (int u = 0; u < T_; u++) { sc[u] = __expf(sc[u] - mx); sum += sc[u]; }
            float inv = 1.0f / sum;
            float o[16] = {};
            for (int u = 0; u < T_; u++) {
                us8 a0 = *(const us8*)&Pt[u * 328 + vc + h * 16];
                us8 bv = *(const us8*)&Pt[u * 328 + vc + h * 16 + 8];
                float ww = sc[u] * inv;
#pragma unroll
                for (int f = 0; f < 8; f++) { o[f] += ww * b2f(a0[f]); o[8 + f] += ww * b2f(bv[f]); }
            }
            unsigned short* orow = aa.st + (((size_t)(b * T_ + t) * N_) + n) * 256 + (part ? 192 : 128) + h * 16;
            us8 w0, w1;
#pragma unroll
            for (int f = 0; f < 8; f++) { w0[f] = f2bs_r(o[f]); w1[f] = f2bs_r(o[8 + f]); }
            *(us8*)orow = w0;
            *(us8*)(orow + 8) = w1;
        }
    }
}

// ===========================================================================
// Output projection (128x64 tile, 768 blocks -> 3/CU), fp32 out, folded bias.
// ===========================================================================
__global__ __launch_bounds__(256) void out_proj(
    const unsigned short* __restrict__ A, const unsigned short* __restrict__ W,
    const float* __restrict__ bias, float* __restrict__ O)
{
    __shared__ unsigned short As[128 * 64];
    __shared__ unsigned short Ws[64 * 64];
    const int m0 = blockIdx.x * 128;
    const int e0 = blockIdx.y * 64;
    const int tid = threadIdx.x;
    const int lane = tid & 63;
    const int wid = tid >> 6;
    const int wm = wid >> 1, wn = wid & 1;
    const int l15 = lane & 15, l4 = lane >> 4;
    const int K = 256;

    f32x4 acc[4][2];
#pragma unroll
    for (int i = 0; i < 4; i++)
#pragma unroll
        for (int j = 0; j < 2; j++)
#pragma unroll
            for (int r = 0; r < 4; r++) acc[i][j][r] = 0.f;

    for (int kk = 0; kk < K; kk += 64) {
#pragma unroll
        for (int p = 0; p < 4; p++) {
            int off = p * 2048 + tid * 8;
            int r = off >> 6, cc = off & 63;
            GLOAD16(&A[(size_t)(m0 + r) * K + kk + cc], &As[p * 2048 + wid * 512]);
        }
#pragma unroll
        for (int p = 0; p < 2; p++) {
            int off = p * 2048 + tid * 8;
            int r = off >> 6, cc = off & 63;
            GLOAD16(&W[(size_t)(e0 + r) * K + kk + cc], &Ws[p * 2048 + wid * 512]);
        }
        __syncthreads();
#pragma unroll
        for (int ks = 0; ks < 64; ks += 32) {
            bf16x8 af[4], bw[2];
#pragma unroll
            for (int i = 0; i < 4; i++)
                af[i] = *(bf16x8*)(&As[(wm * 64 + i * 16 + l15) * 64 + ks + l4 * 8]);
#pragma unroll
            for (int j = 0; j < 2; j++)
                bw[j] = *(bf16x8*)(&Ws[(wn * 32 + j * 16 + l15) * 64 + ks + l4 * 8]);
#pragma unroll
            for (int i = 0; i < 4; i++)
#pragma unroll
                for (int j = 0; j < 2; j++)
                    acc[i][j] = __builtin_amdgcn_mfma_f32_16x16x32_bf16(af[i], bw[j], acc[i][j], 0, 0, 0);
        }
        __syncthreads();
    }

#pragma unroll
    for (int i = 0; i < 4; i++)
#pragma unroll
        for (int j = 0; j < 2; j++) {
            int row0 = m0 + wm * 64 + i * 16 + l4 * 4;
            int col = e0 + wn * 32 + j * 16 + l15;
            float bv = bias[col];
#pragma unroll
            for (int r = 0; r < 4; r++)
                O[(size_t)(row0 + r) * 256 + col] = acc[i][j][r] + bv;
        }
}

// ===========================================================================
extern "C" void kernel_launch(void* const* d_in, const int* in_sizes, int n_in,
                              void* d_out, int out_size, void* d_ws, size_t ws_size,
                              hipStream_t stream)
{
    const float* x      = (const float*)d_in[0];
    const float* dtw0   = (const float*)d_in[1];
    const float* dtw1   = (const float*)d_in[2];
    const float* map0   = (const float*)d_in[3];
    const float* map1   = (const float*)d_in[4];
    const float* tmpinf = (const float*)d_in[5];
    const float* lq1    = (const float*)d_in[9];
    const float* lk1    = (const float*)d_in[10];
    const float* lq2    = (const float*)d_in[11];
    const float* lk2    = (const float*)d_in[12];
    const float* subln  = (const float*)d_in[13];
    const float* Wagg_f = (const float*)d_in[20];
    const float* b_agg  = (const float*)d_in[21];
    const float* tq     = (const float*)d_in[25];
    const float* Wout_f = (const float*)d_in[28];
    float* out = (float*)d_out;

    const size_t M = (size_t)BT_ * N_;   // 24576

    char* w = (char*)d_ws;
    unsigned short* P     = (unsigned short*)w;   w += M * 512 * 2;
    unsigned short* st    = (unsigned short*)w;   w += M * 256 * 2;
    unsigned short* qkv0b = (unsigned short*)w;   w += (size_t)BT_ * 64 * 192 * 2;
    unsigned short* qkv1b = (unsigned short*)w;   w += (size_t)BT_ * 128 * 192 * 2;
    unsigned short* xb    = (unsigned short*)w;   w += M * 256 * 2;
    unsigned short* d0b   = (unsigned short*)w;   w += (size_t)BT_ * 64 * 256 * 2;
    unsigned short* d1b   = (unsigned short*)w;   w += (size_t)BT_ * 128 * 256 * 2;
    unsigned short* wb    = (unsigned short*)w;   w += 299008 * 2;
    float*          bvec  = (float*)w;            w += 256 * 4;

    unsigned short* Wproj = wb;
    unsigned short* Wd0   = wb + 131072;
    unsigned short* Wd1   = wb + 180224;
    unsigned short* Weff  = wb + 233472;

    dim3 blk(256);

    // 1. conversions + Wagg fold (disjoint writes within one launch)
    ConvArgs ca;
    ca.x = x; ca.d0 = dtw0; ca.d1 = dtw1;
    ca.wp[0] = (const float*)d_in[6];  ca.wp[1] = (const float*)d_in[7];  ca.wp[2] = (const float*)d_in[8];
    ca.wp[3] = (const float*)d_in[22]; ca.wp[4] = (const float*)d_in[23]; ca.wp[5] = (const float*)d_in[24];
    ca.wp[6] = (const float*)d_in[26]; ca.wp[7] = (const float*)d_in[27];
    ca.wp[8] = (const float*)d_in[14]; ca.wp[9] = (const float*)d_in[15]; ca.wp[10] = (const float*)d_in[16];
    ca.wp[11] = (const float*)d_in[17]; ca.wp[12] = (const float*)d_in[18]; ca.wp[13] = (const float*)d_in[19];
    ca.wp[14] = Wagg_f; ca.wp[15] = Wout_f;
    ca.bagg = b_agg;
    ca.xb = xb; ca.d0b = d0b; ca.d1b = d1b; ca.wb = wb; ca.bvec = bvec;
    hipLaunchKernelGGL(prep_all, dim3(NCONVBLK + 16), blk, 0, stream, ca);

    // 2. all projections (P + dtw) in one launch
    ProjArgs pa;
    pa.xb = xb; pa.Wproj = Wproj;
    pa.d0b = d0b; pa.d1b = d1b; pa.Wd0 = Wd0; pa.Wd1 = Wd1;
    pa.P = P; pa.q0b = qkv0b; pa.q1b = qkv1b;
    hipLaunchKernelGGL(proj_all, dim3(984), blk, 0, stream, pa);

    // 3. all attention branches in one launch (balanced XCD swizzle)
    AttnArgs aa;
    aa.P = P; aa.qkv0 = qkv0b; aa.qkv1 = qkv1b;
    aa.map0 = map0; aa.map1 = map1;
    aa.lq1 = lq1; aa.lk1 = lk1; aa.lq2 = lq2; aa.lk2 = lk2; aa.subln = subln;
    aa.tq = tq; aa.ti = tmpinf; aa.st = st;
    hipLaunchKernelGGL(attn_all, dim3(3328), blk, 0, stream, aa);

    // 4. output projection (128x64 tile, 768 blocks)
    hipLaunchKernelGGL(out_proj, dim3(192, 4), blk, 0, stream,
                       st, Weff, bvec, out);
}